// Round 3
// baseline (3152.795 us; speedup 1.0000x reference)
//
#include <hip/hip_runtime.h>
#include <math.h>

typedef __bf16 bf16;
typedef __bf16 bf16x8 __attribute__((ext_vector_type(8)));
typedef float f32x4 __attribute__((ext_vector_type(4)));

#define HN 256
#define EFN 128
#define KIN 384
#define G3 768
#define KMIXN 20

__device__ __forceinline__ float sigf(float x) { return 1.0f / (1.0f + __expf(-x)); }

// load 8 consecutive f32, round to bf16x8
__device__ __forceinline__ bf16x8 ld8f(const float* __restrict__ p) {
  f32x4 a = *(const f32x4*)p, b = *(const f32x4*)(p + 4);
  bf16x8 v;
  v[0] = (bf16)a[0]; v[1] = (bf16)a[1]; v[2] = (bf16)a[2]; v[3] = (bf16)a[3];
  v[4] = (bf16)b[0]; v[5] = (bf16)b[1]; v[6] = (bf16)b[2]; v[7] = (bf16)b[3];
  return v;
}

// ---------------- flag sum ----------------
__global__ void ksum(const float* __restrict__ flags, int n, float* __restrict__ scal) {
  __shared__ float red[4];
  float s = 0.f;
  for (int i = blockIdx.x * blockDim.x + threadIdx.x; i < n; i += gridDim.x * blockDim.x)
    s += flags[i];
  #pragma unroll
  for (int o = 32; o > 0; o >>= 1) s += __shfl_down(s, o, 64);
  int lane = threadIdx.x & 63, w = threadIdx.x >> 6;
  if (lane == 0) red[w] = s;
  __syncthreads();
  if (threadIdx.x == 0) atomicAdd(scal, red[0] + red[1] + red[2] + red[3]);
}

// ---------------- state init + bpr (one wave per node) ----------------
__global__ void kinit(const int* __restrict__ user_idx, const int* __restrict__ node_idx_feat,
                      const float* __restrict__ flags, const float* __restrict__ users,
                      const float* __restrict__ items, float* __restrict__ S,
                      float* __restrict__ bpr_out, const float* __restrict__ scal, int n) {
  int lane = threadIdx.x & 63;
  int gw = (blockIdx.x * blockDim.x + threadIdx.x) >> 6;
  int nw = (gridDim.x * blockDim.x) >> 6;
  float sp = scal[0];
  float sn = (float)n - sp;
  for (int i = gw; i < n; i += nw) {
    int u = user_idx[i], it = node_idx_feat[i];
    f32x4 uv = *(const f32x4*)(users + (size_t)u * HN + lane * 4);
    f32x4 iv = *(const f32x4*)(items + (size_t)it * HN + lane * 4);
    *(f32x4*)(S + (size_t)i * HN + lane * 4) = iv;
    float d = uv[0] * iv[0] + uv[1] * iv[1] + uv[2] * iv[2] + uv[3] * iv[3];
    #pragma unroll
    for (int o = 32; o > 0; o >>= 1) d += __shfl_down(d, o, 64);
    if (lane == 0) {
      float f = flags[i];
      float x = (1.f - f) * d / sn - f * d / sp;
      float b = (x > 20.f) ? x : log1pf(expf(x));
      bpr_out[i] = b;
    }
  }
}

// ---------------- stage-1 GEMM with fused edge-input gather ----------------
// C[e, :NO] = relu( [S[a]-S[b] | masked noise] @ W[NO,384]^T + bias )
__global__ __launch_bounds__(256) void kgemmE(const int* __restrict__ edges,
                                              const int* __restrict__ att_idx,
                                              const float* __restrict__ noise,
                                              const float* __restrict__ S,
                                              const float* __restrict__ W,
                                              const float* __restrict__ bias,
                                              bf16* __restrict__ C, int E, int NO) {
  __shared__ bf16 As[128][72];
  __shared__ bf16 Bs[128][72];
  __shared__ int ea[128], eb[128];
  __shared__ unsigned char em[128];
  const int bm0 = blockIdx.x * 128, bn0 = blockIdx.y * 128;
  const int tid = threadIdx.x, lane = tid & 63, w = tid >> 6;
  const int wm = w >> 1, wn = w & 1, lr = lane & 15, lk = lane >> 4;
  const int lrow = tid >> 3, lcol = (tid & 7) * 8;
  if (tid < 128) {
    int e = bm0 + tid;
    int a = 0, b = 0; unsigned char m = 0;
    if (e < E) {
      a = edges[2 * e]; b = edges[2 * e + 1];
      m = (att_idx[a] > 0) || (att_idx[b] > 0);
    }
    ea[tid] = a; eb[tid] = b; em[tid] = m;
  }
  __syncthreads();
  f32x4 acc[4][4] = {};
  for (int k0 = 0; k0 < KIN; k0 += 64) {
    #pragma unroll
    for (int p = 0; p < 4; p++) {
      int r = lrow + p * 32;
      bf16x8 v;
      if (k0 < HN) {
        const float* pa = S + (size_t)ea[r] * HN + k0 + lcol;
        const float* pb = S + (size_t)eb[r] * HN + k0 + lcol;
        f32x4 a0 = *(const f32x4*)pa, a1 = *(const f32x4*)(pa + 4);
        f32x4 b0 = *(const f32x4*)pb, b1 = *(const f32x4*)(pb + 4);
        v[0] = (bf16)(a0[0] - b0[0]); v[1] = (bf16)(a0[1] - b0[1]);
        v[2] = (bf16)(a0[2] - b0[2]); v[3] = (bf16)(a0[3] - b0[3]);
        v[4] = (bf16)(a1[0] - b1[0]); v[5] = (bf16)(a1[1] - b1[1]);
        v[6] = (bf16)(a1[2] - b1[2]); v[7] = (bf16)(a1[3] - b1[3]);
      } else {
        if (em[r]) v = ld8f(noise + (size_t)(bm0 + r) * EFN + (k0 - HN) + lcol);
        else { bf16 z = (bf16)0.f; v[0]=z;v[1]=z;v[2]=z;v[3]=z;v[4]=z;v[5]=z;v[6]=z;v[7]=z; }
      }
      *(bf16x8*)(&As[r][lcol]) = v;
      *(bf16x8*)(&Bs[r][lcol]) = ld8f(W + (size_t)(bn0 + r) * KIN + k0 + lcol);
    }
    __syncthreads();
    #pragma unroll
    for (int kk = 0; kk < 2; kk++) {
      bf16x8 af[4], bfr[4];
      #pragma unroll
      for (int m = 0; m < 4; m++) af[m] = *(const bf16x8*)(&As[wm * 64 + m * 16 + lr][kk * 32 + lk * 8]);
      #pragma unroll
      for (int n = 0; n < 4; n++) bfr[n] = *(const bf16x8*)(&Bs[wn * 64 + n * 16 + lr][kk * 32 + lk * 8]);
      #pragma unroll
      for (int m = 0; m < 4; m++)
        #pragma unroll
        for (int n = 0; n < 4; n++)
          acc[m][n] = __builtin_amdgcn_mfma_f32_16x16x32_bf16(af[m], bfr[n], acc[m][n], 0, 0, 0);
    }
    __syncthreads();
  }
  #pragma unroll
  for (int n = 0; n < 4; n++) {
    int gc = bn0 + wn * 64 + n * 16 + lr;
    float bc = bias[gc];
    #pragma unroll
    for (int m = 0; m < 4; m++) {
      #pragma unroll
      for (int j = 0; j < 4; j++) {
        int gr = bm0 + wm * 64 + m * 16 + lk * 4 + j;
        if (gr < E) C[(size_t)gr * NO + gc] = (bf16)fmaxf(acc[m][n][j] + bc, 0.f);
      }
    }
  }
}

// ---------------- fused stage-2: msg2 * sigmoid(att2), atomic scatter into agg ----------------
__global__ __launch_bounds__(256) void kmsg2(const bf16* __restrict__ Hatt, const float* __restrict__ Watt,
                                             const float* __restrict__ batt, const bf16* __restrict__ Hmsg,
                                             const float* __restrict__ Wmsg, const float* __restrict__ bmsg,
                                             const int* __restrict__ edges, float* __restrict__ agg, int E) {
  __shared__ bf16 As[128][72];
  __shared__ bf16 Bs[128][72];
  const int bm0 = blockIdx.x * 128, bn0 = blockIdx.y * 128;
  const int tid = threadIdx.x, lane = tid & 63, w = tid >> 6;
  const int wm = w >> 1, wn = w & 1, lr = lane & 15, lk = lane >> 4;
  const int lrow = tid >> 3, lcol = (tid & 7) * 8;

  f32x4 acc_a[4][4] = {};
  for (int k0 = 0; k0 < EFN; k0 += 64) {
    #pragma unroll
    for (int p = 0; p < 4; p++) {
      int r = lrow + p * 32;
      int gr = bm0 + r;
      bf16x8 va;
      if (gr < E) va = *(const bf16x8*)(Hatt + (size_t)gr * EFN + k0 + lcol);
      else { bf16 z = (bf16)0.f; va[0]=z;va[1]=z;va[2]=z;va[3]=z;va[4]=z;va[5]=z;va[6]=z;va[7]=z; }
      *(bf16x8*)(&As[r][lcol]) = va;
      *(bf16x8*)(&Bs[r][lcol]) = ld8f(Watt + (size_t)(bn0 + r) * EFN + k0 + lcol);
    }
    __syncthreads();
    #pragma unroll
    for (int kk = 0; kk < 2; kk++) {
      bf16x8 af[4], bfr[4];
      #pragma unroll
      for (int m = 0; m < 4; m++) af[m] = *(const bf16x8*)(&As[wm * 64 + m * 16 + lr][kk * 32 + lk * 8]);
      #pragma unroll
      for (int n = 0; n < 4; n++) bfr[n] = *(const bf16x8*)(&Bs[wn * 64 + n * 16 + lr][kk * 32 + lk * 8]);
      #pragma unroll
      for (int m = 0; m < 4; m++)
        #pragma unroll
        for (int n = 0; n < 4; n++)
          acc_a[m][n] = __builtin_amdgcn_mfma_f32_16x16x32_bf16(af[m], bfr[n], acc_a[m][n], 0, 0, 0);
    }
    __syncthreads();
  }

  f32x4 acc_m[4][4] = {};
  for (int k0 = 0; k0 < HN; k0 += 64) {
    #pragma unroll
    for (int p = 0; p < 4; p++) {
      int r = lrow + p * 32;
      int gr = bm0 + r;
      bf16x8 va;
      if (gr < E) va = *(const bf16x8*)(Hmsg + (size_t)gr * HN + k0 + lcol);
      else { bf16 z = (bf16)0.f; va[0]=z;va[1]=z;va[2]=z;va[3]=z;va[4]=z;va[5]=z;va[6]=z;va[7]=z; }
      *(bf16x8*)(&As[r][lcol]) = va;
      *(bf16x8*)(&Bs[r][lcol]) = ld8f(Wmsg + (size_t)(bn0 + r) * HN + k0 + lcol);
    }
    __syncthreads();
    #pragma unroll
    for (int kk = 0; kk < 2; kk++) {
      bf16x8 af[4], bfr[4];
      #pragma unroll
      for (int m = 0; m < 4; m++) af[m] = *(const bf16x8*)(&As[wm * 64 + m * 16 + lr][kk * 32 + lk * 8]);
      #pragma unroll
      for (int n = 0; n < 4; n++) bfr[n] = *(const bf16x8*)(&Bs[wn * 64 + n * 16 + lr][kk * 32 + lk * 8]);
      #pragma unroll
      for (int m = 0; m < 4; m++)
        #pragma unroll
        for (int n = 0; n < 4; n++)
          acc_m[m][n] = __builtin_amdgcn_mfma_f32_16x16x32_bf16(af[m], bfr[n], acc_m[m][n], 0, 0, 0);
    }
    __syncthreads();
  }

  float bA[4], bM[4];
  int gcs[4];
  #pragma unroll
  for (int n = 0; n < 4; n++) {
    gcs[n] = bn0 + wn * 64 + n * 16 + lr;
    bA[n] = batt[gcs[n]];
    bM[n] = bmsg[gcs[n]];
  }
  #pragma unroll
  for (int m = 0; m < 4; m++) {
    #pragma unroll
    for (int j = 0; j < 4; j++) {
      int e = bm0 + wm * 64 + m * 16 + lk * 4 + j;
      if (e < E) {
        int dst = edges[2 * e + 1];
        float* ag = agg + (size_t)dst * HN;
        #pragma unroll
        for (int n = 0; n < 4; n++) {
          float a = sigf(acc_a[m][n][j] + bA[n]);
          float v = (acc_m[m][n][j] + bM[n]) * a;
          atomicAdd(ag + gcs[n], v);
        }
      }
    }
  }
}

// ---------------- GRU GEMM: C[M,NO](bf16) = A_f32[M,256] @ W_f32[NO,256]^T + bias ----------------
__global__ __launch_bounds__(256) void kgemmF(const float* __restrict__ A, const float* __restrict__ W,
                                              const float* __restrict__ bias, bf16* __restrict__ C,
                                              int M, int NO) {
  __shared__ bf16 As[128][72];
  __shared__ bf16 Bs[128][72];
  const int bm0 = blockIdx.x * 128, bn0 = blockIdx.y * 128;
  const int tid = threadIdx.x, lane = tid & 63, w = tid >> 6;
  const int wm = w >> 1, wn = w & 1, lr = lane & 15, lk = lane >> 4;
  const int lrow = tid >> 3, lcol = (tid & 7) * 8;
  f32x4 acc[4][4] = {};
  for (int k0 = 0; k0 < HN; k0 += 64) {
    #pragma unroll
    for (int p = 0; p < 4; p++) {
      int r = lrow + p * 32;
      int gr = bm0 + r;
      bf16x8 v;
      if (gr < M) v = ld8f(A + (size_t)gr * HN + k0 + lcol);
      else { bf16 z = (bf16)0.f; v[0]=z;v[1]=z;v[2]=z;v[3]=z;v[4]=z;v[5]=z;v[6]=z;v[7]=z; }
      *(bf16x8*)(&As[r][lcol]) = v;
      *(bf16x8*)(&Bs[r][lcol]) = ld8f(W + (size_t)(bn0 + r) * HN + k0 + lcol);
    }
    __syncthreads();
    #pragma unroll
    for (int kk = 0; kk < 2; kk++) {
      bf16x8 af[4], bfr[4];
      #pragma unroll
      for (int m = 0; m < 4; m++) af[m] = *(const bf16x8*)(&As[wm * 64 + m * 16 + lr][kk * 32 + lk * 8]);
      #pragma unroll
      for (int n = 0; n < 4; n++) bfr[n] = *(const bf16x8*)(&Bs[wn * 64 + n * 16 + lr][kk * 32 + lk * 8]);
      #pragma unroll
      for (int m = 0; m < 4; m++)
        #pragma unroll
        for (int n = 0; n < 4; n++)
          acc[m][n] = __builtin_amdgcn_mfma_f32_16x16x32_bf16(af[m], bfr[n], acc[m][n], 0, 0, 0);
    }
    __syncthreads();
  }
  #pragma unroll
  for (int n = 0; n < 4; n++) {
    int gc = bn0 + wn * 64 + n * 16 + lr;
    float bc = bias[gc];
    #pragma unroll
    for (int m = 0; m < 4; m++) {
      #pragma unroll
      for (int j = 0; j < 4; j++) {
        int gr = bm0 + wm * 64 + m * 16 + lk * 4 + j;
        if (gr < M) C[(size_t)gr * NO + gc] = (bf16)(acc[m][n][j] + bc);
      }
    }
  }
}

// ---------------- head GEMM-1 with fused pair-diff gather ----------------
__global__ __launch_bounds__(256) void kgemmP(const int* __restrict__ pidx, const float* __restrict__ S,
                                              const float* __restrict__ W, const float* __restrict__ bias,
                                              bf16* __restrict__ C, int M, int NO) {
  __shared__ bf16 As[128][72];
  __shared__ bf16 Bs[128][72];
  __shared__ int ia[128], ib[128];
  const int bm0 = blockIdx.x * 128, bn0 = blockIdx.y * 128;
  const int tid = threadIdx.x, lane = tid & 63, w = tid >> 6;
  const int wm = w >> 1, wn = w & 1, lr = lane & 15, lk = lane >> 4;
  const int lrow = tid >> 3, lcol = (tid & 7) * 8;
  if (tid < 128) {
    int p = bm0 + tid;
    int a = 0, b = 0;
    if (p < M) { a = pidx[2 * p]; b = pidx[2 * p + 1]; }
    ia[tid] = a; ib[tid] = b;
  }
  __syncthreads();
  f32x4 acc[4][4] = {};
  for (int k0 = 0; k0 < HN; k0 += 64) {
    #pragma unroll
    for (int p = 0; p < 4; p++) {
      int r = lrow + p * 32;
      const float* pa = S + (size_t)ia[r] * HN + k0 + lcol;
      const float* pb = S + (size_t)ib[r] * HN + k0 + lcol;
      f32x4 a0 = *(const f32x4*)pa, a1 = *(const f32x4*)(pa + 4);
      f32x4 b0 = *(const f32x4*)pb, b1 = *(const f32x4*)(pb + 4);
      bf16x8 v;
      v[0] = (bf16)(a0[0] - b0[0]); v[1] = (bf16)(a0[1] - b0[1]);
      v[2] = (bf16)(a0[2] - b0[2]); v[3] = (bf16)(a0[3] - b0[3]);
      v[4] = (bf16)(a1[0] - b1[0]); v[5] = (bf16)(a1[1] - b1[1]);
      v[6] = (bf16)(a1[2] - b1[2]); v[7] = (bf16)(a1[3] - b1[3]);
      *(bf16x8*)(&As[r][lcol]) = v;
      *(bf16x8*)(&Bs[r][lcol]) = ld8f(W + (size_t)(bn0 + r) * HN + k0 + lcol);
    }
    __syncthreads();
    #pragma unroll
    for (int kk = 0; kk < 2; kk++) {
      bf16x8 af[4], bfr[4];
      #pragma unroll
      for (int m = 0; m < 4; m++) af[m] = *(const bf16x8*)(&As[wm * 64 + m * 16 + lr][kk * 32 + lk * 8]);
      #pragma unroll
      for (int n = 0; n < 4; n++) bfr[n] = *(const bf16x8*)(&Bs[wn * 64 + n * 16 + lr][kk * 32 + lk * 8]);
      #pragma unroll
      for (int m = 0; m < 4; m++)
        #pragma unroll
        for (int n = 0; n < 4; n++)
          acc[m][n] = __builtin_amdgcn_mfma_f32_16x16x32_bf16(af[m], bfr[n], acc[m][n], 0, 0, 0);
    }
    __syncthreads();
  }
  #pragma unroll
  for (int n = 0; n < 4; n++) {
    int gc = bn0 + wn * 64 + n * 16 + lr;
    float bc = bias[gc];
    #pragma unroll
    for (int m = 0; m < 4; m++) {
      #pragma unroll
      for (int j = 0; j < 4; j++) {
        int gr = bm0 + wm * 64 + m * 16 + lk * 4 + j;
        if (gr < M) C[(size_t)gr * NO + gc] = (bf16)fmaxf(acc[m][n][j] + bc, 0.f);
      }
    }
  }
}

// ---------------- head GEMM-2: bf16 A, f32 W, relu, bf16 out ----------------
__global__ __launch_bounds__(256) void kgemmB(const bf16* __restrict__ A, const float* __restrict__ W,
                                              const float* __restrict__ bias, bf16* __restrict__ C,
                                              int M, int NO) {
  __shared__ bf16 As[128][72];
  __shared__ bf16 Bs[128][72];
  const int bm0 = blockIdx.x * 128, bn0 = blockIdx.y * 128;
  const int tid = threadIdx.x, lane = tid & 63, w = tid >> 6;
  const int wm = w >> 1, wn = w & 1, lr = lane & 15, lk = lane >> 4;
  const int lrow = tid >> 3, lcol = (tid & 7) * 8;
  f32x4 acc[4][4] = {};
  for (int k0 = 0; k0 < HN; k0 += 64) {
    #pragma unroll
    for (int p = 0; p < 4; p++) {
      int r = lrow + p * 32;
      int gr = bm0 + r;
      bf16x8 v;
      if (gr < M) v = *(const bf16x8*)(A + (size_t)gr * HN + k0 + lcol);
      else { bf16 z = (bf16)0.f; v[0]=z;v[1]=z;v[2]=z;v[3]=z;v[4]=z;v[5]=z;v[6]=z;v[7]=z; }
      *(bf16x8*)(&As[r][lcol]) = v;
      *(bf16x8*)(&Bs[r][lcol]) = ld8f(W + (size_t)(bn0 + r) * HN + k0 + lcol);
    }
    __syncthreads();
    #pragma unroll
    for (int kk = 0; kk < 2; kk++) {
      bf16x8 af[4], bfr[4];
      #pragma unroll
      for (int m = 0; m < 4; m++) af[m] = *(const bf16x8*)(&As[wm * 64 + m * 16 + lr][kk * 32 + lk * 8]);
      #pragma unroll
      for (int n = 0; n < 4; n++) bfr[n] = *(const bf16x8*)(&Bs[wn * 64 + n * 16 + lr][kk * 32 + lk * 8]);
      #pragma unroll
      for (int m = 0; m < 4; m++)
        #pragma unroll
        for (int n = 0; n < 4; n++)
          acc[m][n] = __builtin_amdgcn_mfma_f32_16x16x32_bf16(af[m], bfr[n], acc[m][n], 0, 0, 0);
    }
    __syncthreads();
  }
  #pragma unroll
  for (int n = 0; n < 4; n++) {
    int gc = bn0 + wn * 64 + n * 16 + lr;
    float bc = bias[gc];
    #pragma unroll
    for (int m = 0; m < 4; m++) {
      #pragma unroll
      for (int j = 0; j < 4; j++) {
        int gr = bm0 + wm * 64 + m * 16 + lk * 4 + j;
        if (gr < M) C[(size_t)gr * NO + gc] = (bf16)fmaxf(acc[m][n][j] + bc, 0.f);
      }
    }
  }
}

// ---------------- GRU gate ----------------
__global__ void kgate(const bf16* __restrict__ gi, const bf16* __restrict__ gh,
                      float* __restrict__ S, int n, int dorelu) {
  int total = n * 32;
  for (int id = blockIdx.x * blockDim.x + threadIdx.x; id < total; id += gridDim.x * blockDim.x) {
    int i = id >> 5;
    int h = (id & 31) * 8;
    const bf16* pgi = gi + (size_t)i * G3 + h;
    const bf16* pgh = gh + (size_t)i * G3 + h;
    bf16x8 gr8 = *(const bf16x8*)(pgi);
    bf16x8 hr8 = *(const bf16x8*)(pgh);
    bf16x8 gz8 = *(const bf16x8*)(pgi + HN);
    bf16x8 hz8 = *(const bf16x8*)(pgh + HN);
    bf16x8 gn8 = *(const bf16x8*)(pgi + 2 * HN);
    bf16x8 hn8 = *(const bf16x8*)(pgh + 2 * HN);
    float* ps = S + (size_t)i * HN + h;
    f32x4 h0 = *(const f32x4*)ps;
    f32x4 h1 = *(const f32x4*)(ps + 4);
    float o[8];
    #pragma unroll
    for (int j = 0; j < 8; j++) {
      float hv = (j < 4) ? h0[j] : h1[j - 4];
      float r = sigf((float)gr8[j] + (float)hr8[j]);
      float z = sigf((float)gz8[j] + (float)hz8[j]);
      float nn = tanhf((float)gn8[j] + r * (float)hn8[j]);
      float s = (1.f - z) * nn + z * hv;
      o[j] = dorelu ? fmaxf(s, 0.f) : s;
    }
    f32x4 o0, o1;
    o0[0]=o[0];o0[1]=o[1];o0[2]=o[2];o0[3]=o[3];
    o1[0]=o[4];o1[1]=o[5];o1[2]=o[6];o1[3]=o[7];
    *(f32x4*)ps = o0;
    *(f32x4*)(ps + 4) = o1;
  }
}

// ---------------- final 20-col head: out[P,20] = Hb[P,256] @ W[20,256]^T + b ----------------
__global__ __launch_bounds__(256) void khead_out(const bf16* __restrict__ Hb, const float* __restrict__ W,
                                                 const float* __restrict__ bias, float* __restrict__ out, int P) {
  __shared__ float Wl[KMIXN][256];
  __shared__ float bl[KMIXN];
  for (int i = threadIdx.x; i < KMIXN * 256; i += 256) Wl[i >> 8][i & 255] = W[i];
  if (threadIdx.x < KMIXN) bl[threadIdx.x] = bias[threadIdx.x];
  __syncthreads();
  int lane = threadIdx.x & 63;
  int wv = threadIdx.x >> 6;
  for (int p = blockIdx.x * 4 + wv; p < P; p += gridDim.x * 4) {
    bf16x8 hv = *(const bf16x8*)(Hb + (size_t)p * HN + lane * 4);
    // note: lane*4 over 64 lanes covers 256 with 4 elems each; use 4 of the 8 loaded
    float h0 = (float)hv[0], h1 = (float)hv[1], h2 = (float)hv[2], h3 = (float)hv[3];
    float pk[KMIXN];
    #pragma unroll
    for (int k = 0; k < KMIXN; k++) {
      const float* wr = &Wl[k][lane * 4];
      pk[k] = h0 * wr[0] + h1 * wr[1] + h2 * wr[2] + h3 * wr[3];
    }
    #pragma unroll
    for (int k = 0; k < KMIXN; k++)
      #pragma unroll
      for (int o = 32; o > 0; o >>= 1) pk[k] += __shfl_down(pk[k], o, 64);
    if (lane == 0) {
      #pragma unroll
      for (int k = 0; k < KMIXN; k++) out[(size_t)p * KMIXN + k] = pk[k] + bl[k];
    }
  }
}

extern "C" void kernel_launch(void* const* d_in, const int* in_sizes, int n_in,
                              void* d_out, int out_size, void* d_ws, size_t ws_size,
                              hipStream_t stream) {
  const int* user_idx = (const int*)d_in[0];
  const int* node_idx_feat = (const int*)d_in[1];
  const float* pos_flag = (const float*)d_in[2];
  const int* edges = (const int*)d_in[3];
  const int* node_idx_gnn = (const int*)d_in[4];
  const int* att_idx = (const int*)d_in[5];
  const float* att_noise = (const float*)d_in[6];
  const float* users = (const float*)d_in[7];
  const float* items = (const float*)d_in[8];
  const float* msg_w1 = (const float*)d_in[9];
  const float* msg_b1 = (const float*)d_in[10];
  const float* msg_w2 = (const float*)d_in[11];
  const float* msg_b2 = (const float*)d_in[12];
  const float* att_w1 = (const float*)d_in[13];
  const float* att_b1 = (const float*)d_in[14];
  const float* att_w2 = (const float*)d_in[15];
  const float* att_b2 = (const float*)d_in[16];
  const float* gru_wih = (const float*)d_in[17];
  const float* gru_bih = (const float*)d_in[18];
  const float* gru_whh = (const float*)d_in[19];
  const float* gru_bhh = (const float*)d_in[20];
  const float* theta_w1 = (const float*)d_in[21];
  const float* theta_b1 = (const float*)d_in[22];
  const float* theta_w2 = (const float*)d_in[23];
  const float* theta_b2 = (const float*)d_in[24];
  const float* theta_w3 = (const float*)d_in[25];
  const float* theta_b3 = (const float*)d_in[26];
  const float* alpha_w1 = (const float*)d_in[27];
  const float* alpha_b1 = (const float*)d_in[28];
  const float* alpha_w2 = (const float*)d_in[29];
  const float* alpha_b2 = (const float*)d_in[30];
  const float* alpha_w3 = (const float*)d_in[31];
  const float* alpha_b3 = (const float*)d_in[32];

  const int N = in_sizes[0];
  const int E = in_sizes[3] / 2;
  const int P = in_sizes[4] / 2;

  float* out_theta = (float*)d_out;
  float* out_alpha = out_theta + (size_t)P * KMIXN;
  float* out_bpr = out_theta + 2 * (size_t)P * KMIXN;

  // ---- workspace carve (~256 MB decimal) ----
  char* ws = (char*)d_ws;
  size_t szS = (size_t)N * HN * 4;             // 51.2 MB  f32 state
  size_t szHm = (size_t)E * HN * 2;            // 102.4 MB bf16
  size_t szHa = (size_t)E * EFN * 2;           // 51.2 MB  bf16
  size_t szGIb = (size_t)N * G3 * 2;           // 76.8 MB  bf16
  int PC = (P + 1) / 2;
  size_t szH1 = (size_t)PC * HN * 2;           // 51.2 MB  bf16
  size_t szX = szHm + szHa;
  if (2 * szGIb > szX) szX = 2 * szGIb;
  if (2 * szH1 > szX) szX = 2 * szH1;
  size_t szAgg = (size_t)N * HN * 4;           // 51.2 MB  f32

  size_t offX = szS;
  size_t offAgg = offX + szX;
  size_t offScal = offAgg + szAgg;

  float* S = (float*)ws;
  bf16* Hmsg = (bf16*)(ws + offX);
  bf16* Hatt = (bf16*)(ws + offX + szHm);
  bf16* gi = (bf16*)(ws + offX);
  bf16* gh = (bf16*)(ws + offX + szGIb);
  bf16* h1 = (bf16*)(ws + offX);
  bf16* h2 = (bf16*)(ws + offX + szH1);
  float* agg = (float*)(ws + offAgg);
  float* scal = (float*)(ws + offScal);

  const int gE = (E + 127) / 128;
  const int gN = (N + 127) / 128;

  hipMemsetAsync(scal, 0, 4, stream);
  ksum<<<256, 256, 0, stream>>>(pos_flag, N, scal);
  kinit<<<1024, 256, 0, stream>>>(user_idx, node_idx_feat, pos_flag, users, items, S, out_bpr, scal, N);

  for (int li = 0; li < 2; li++) {
    kgemmE<<<dim3(gE, 1), 256, 0, stream>>>(edges, att_idx, att_noise, S,
                                            att_w1 + (size_t)li * EFN * KIN, att_b1 + li * EFN,
                                            Hatt, E, EFN);
    kgemmE<<<dim3(gE, 2), 256, 0, stream>>>(edges, att_idx, att_noise, S,
                                            msg_w1 + (size_t)li * HN * KIN, msg_b1 + li * HN,
                                            Hmsg, E, HN);
    hipMemsetAsync(agg, 0, szAgg, stream);
    kmsg2<<<dim3(gE, 2), 256, 0, stream>>>(Hatt, att_w2 + (size_t)li * HN * EFN, att_b2 + li * HN,
                                           Hmsg, msg_w2 + (size_t)li * HN * HN, msg_b2 + li * HN,
                                           edges, agg, E);
    kgemmF<<<dim3(gN, 6), 256, 0, stream>>>(agg, gru_wih + (size_t)li * G3 * HN,
                                            gru_bih + li * G3, gi, N, G3);
    kgemmF<<<dim3(gN, 6), 256, 0, stream>>>(S, gru_whh + (size_t)li * G3 * HN,
                                            gru_bhh + li * G3, gh, N, G3);
    kgate<<<2048, 256, 0, stream>>>(gi, gh, S, N, li == 0 ? 1 : 0);
  }

  // heads, chunked over P to bound scratch
  for (int c = 0; c < 2; c++) {
    int pc0 = c * PC;
    int pcn = (P - pc0 < PC) ? (P - pc0) : PC;
    if (pcn <= 0) break;
    int gPc = (pcn + 127) / 128;
    // theta
    kgemmP<<<dim3(gPc, 2), 256, 0, stream>>>(node_idx_gnn + (size_t)pc0 * 2, S,
                                             theta_w1, theta_b1, h1, pcn, HN);
    kgemmB<<<dim3(gPc, 2), 256, 0, stream>>>(h1, theta_w2, theta_b2, h2, pcn, HN);
    khead_out<<<4096, 256, 0, stream>>>(h2, theta_w3, theta_b3, out_theta + (size_t)pc0 * KMIXN, pcn);
    // alpha
    kgemmP<<<dim3(gPc, 2), 256, 0, stream>>>(node_idx_gnn + (size_t)pc0 * 2, S,
                                             alpha_w1, alpha_b1, h1, pcn, HN);
    kgemmB<<<dim3(gPc, 2), 256, 0, stream>>>(h1, alpha_w2, alpha_b2, h2, pcn, HN);
    khead_out<<<4096, 256, 0, stream>>>(h2, alpha_w3, alpha_b3, out_alpha + (size_t)pc0 * KMIXN, pcn);
  }
}

// Round 4
// 2727.018 us; speedup vs baseline: 1.1561x; 1.1561x over previous
//
#include <hip/hip_runtime.h>
#include <math.h>

typedef __bf16 bf16;
typedef __bf16 bf16x8 __attribute__((ext_vector_type(8)));
typedef __bf16 bf16x4 __attribute__((ext_vector_type(4)));
typedef float f32x4 __attribute__((ext_vector_type(4)));

#define HN 256
#define EFN 128
#define KIN 384
#define G3 768
#define KMIXN 20

__device__ __forceinline__ float sigf(float x) { return 1.0f / (1.0f + __expf(-x)); }

__device__ __forceinline__ bf16x8 ld8f(const float* __restrict__ p) {
  f32x4 a = *(const f32x4*)p, b = *(const f32x4*)(p + 4);
  bf16x8 v;
  v[0] = (bf16)a[0]; v[1] = (bf16)a[1]; v[2] = (bf16)a[2]; v[3] = (bf16)a[3];
  v[4] = (bf16)b[0]; v[5] = (bf16)b[1]; v[6] = (bf16)b[2]; v[7] = (bf16)b[3];
  return v;
}
__device__ __forceinline__ bf16x8 zero8() {
  bf16x8 v; bf16 z = (bf16)0.f;
  v[0]=z;v[1]=z;v[2]=z;v[3]=z;v[4]=z;v[5]=z;v[6]=z;v[7]=z; return v;
}

// ---------------- weight f32->bf16 (all arrays in one launch) ----------------
struct WList { const float* s[10]; int c[11]; };
__global__ void kwcvt(WList wl, bf16* __restrict__ wb) {
  int total = wl.c[10];
  for (int id = blockIdx.x * blockDim.x + threadIdx.x; id < total; id += gridDim.x * blockDim.x) {
    int i = 0;
    #pragma unroll
    for (int k = 1; k < 10; k++) if (id >= wl.c[k]) i = k;
    wb[id] = (bf16)wl.s[i][id - wl.c[i]];
  }
}

// ---------------- CSR build ----------------
__global__ void kdeg(const int* __restrict__ edges, int* __restrict__ rp, int E) {
  for (int e = blockIdx.x * blockDim.x + threadIdx.x; e < E; e += gridDim.x * blockDim.x)
    atomicAdd(&rp[edges[2 * e + 1] + 1], 1);
}
__global__ void kscan(int* __restrict__ rp, int n) {  // inclusive scan rp[1..n]
  __shared__ int buf[1024];
  __shared__ int carry;
  if (threadIdx.x == 0) carry = 0;
  __syncthreads();
  for (int base = 1; base <= n; base += 1024) {
    int i = base + threadIdx.x;
    int v = (i <= n) ? rp[i] : 0;
    buf[threadIdx.x] = v;
    __syncthreads();
    for (int o = 1; o < 1024; o <<= 1) {
      int t = (threadIdx.x >= o) ? buf[threadIdx.x - o] : 0;
      __syncthreads();
      buf[threadIdx.x] += t;
      __syncthreads();
    }
    if (i <= n) rp[i] = buf[threadIdx.x] + carry;
    __syncthreads();
    if (threadIdx.x == 0) carry += buf[1023];
    __syncthreads();
  }
}
__global__ void kcpy(const int* __restrict__ rp, int* __restrict__ cur, int n) {
  for (int i = blockIdx.x * blockDim.x + threadIdx.x; i < n; i += gridDim.x * blockDim.x)
    cur[i] = rp[i];
}
__global__ void kfill(const int* __restrict__ edges, int* __restrict__ cur,
                      int* __restrict__ csrA, int* __restrict__ csrB, int* __restrict__ csrE, int E) {
  for (int e = blockIdx.x * blockDim.x + threadIdx.x; e < E; e += gridDim.x * blockDim.x) {
    int a = edges[2 * e], b = edges[2 * e + 1];
    int p = atomicAdd(&cur[b], 1);
    csrA[p] = a; csrB[p] = b; csrE[p] = e;
  }
}

// ---------------- flag sum ----------------
__global__ void ksum(const float* __restrict__ flags, int n, float* __restrict__ scal) {
  __shared__ float red[4];
  float s = 0.f;
  for (int i = blockIdx.x * blockDim.x + threadIdx.x; i < n; i += gridDim.x * blockDim.x)
    s += flags[i];
  #pragma unroll
  for (int o = 32; o > 0; o >>= 1) s += __shfl_down(s, o, 64);
  int lane = threadIdx.x & 63, w = threadIdx.x >> 6;
  if (lane == 0) red[w] = s;
  __syncthreads();
  if (threadIdx.x == 0) atomicAdd(scal, red[0] + red[1] + red[2] + red[3]);
}

// ---------------- state init + bpr ----------------
__global__ void kinit(const int* __restrict__ user_idx, const int* __restrict__ node_idx_feat,
                      const float* __restrict__ flags, const float* __restrict__ users,
                      const float* __restrict__ items, float* __restrict__ S, bf16* __restrict__ Sb,
                      float* __restrict__ bpr_out, const float* __restrict__ scal, int n) {
  int lane = threadIdx.x & 63;
  int gw = (blockIdx.x * blockDim.x + threadIdx.x) >> 6;
  int nw = (gridDim.x * blockDim.x) >> 6;
  float sp = scal[0];
  float sn = (float)n - sp;
  for (int i = gw; i < n; i += nw) {
    int u = user_idx[i], it = node_idx_feat[i];
    f32x4 uv = *(const f32x4*)(users + (size_t)u * HN + lane * 4);
    f32x4 iv = *(const f32x4*)(items + (size_t)it * HN + lane * 4);
    *(f32x4*)(S + (size_t)i * HN + lane * 4) = iv;
    bf16x4 ib;
    ib[0] = (bf16)iv[0]; ib[1] = (bf16)iv[1]; ib[2] = (bf16)iv[2]; ib[3] = (bf16)iv[3];
    *(bf16x4*)(Sb + (size_t)i * HN + lane * 4) = ib;
    float d = uv[0] * iv[0] + uv[1] * iv[1] + uv[2] * iv[2] + uv[3] * iv[3];
    #pragma unroll
    for (int o = 32; o > 0; o >>= 1) d += __shfl_down(d, o, 64);
    if (lane == 0) {
      float f = flags[i];
      float x = (1.f - f) * d / sn - f * d / sp;
      float b = (x > 20.f) ? x : log1pf(expf(x));
      bpr_out[i] = b;
    }
  }
}

// ---------------- stage-1 merged GEMM (CSR-ordered rows, fused gather) ----------------
// y<2: Hmsg cols [y*128..); y==2: Hatt cols [0..128)
__global__ __launch_bounds__(256) void kgemmE(const int* __restrict__ csrA, const int* __restrict__ csrB,
                                              const int* __restrict__ csrE, const int* __restrict__ att_idx,
                                              const float* __restrict__ noise, const bf16* __restrict__ Sb,
                                              const bf16* __restrict__ Wm, const float* __restrict__ bm,
                                              const bf16* __restrict__ Wa, const float* __restrict__ ba,
                                              bf16* __restrict__ Hmsg, bf16* __restrict__ Hatt, int E) {
  __shared__ bf16 As[128][72];
  __shared__ bf16 Bs[128][72];
  __shared__ int ea[128], eb[128], ee[128];
  __shared__ unsigned char em[128];
  const bool isAtt = (blockIdx.y == 2);
  const int bn0 = isAtt ? 0 : blockIdx.y * 128;
  const bf16* W = isAtt ? Wa : Wm;
  const float* bias = isAtt ? ba : bm;
  bf16* C = isAtt ? Hatt : Hmsg;
  const int NO = isAtt ? EFN : HN;
  const int bm0 = blockIdx.x * 128;
  const int tid = threadIdx.x, lane = tid & 63, w = tid >> 6;
  const int wm = w >> 1, wn = w & 1, lr = lane & 15, lk = lane >> 4;
  const int lrow = tid >> 3, lcol = (tid & 7) * 8;
  if (tid < 128) {
    int p = bm0 + tid;
    int a = 0, b = 0, e = 0; unsigned char m = 0;
    if (p < E) {
      a = csrA[p]; b = csrB[p]; e = csrE[p];
      m = (att_idx[a] > 0) || (att_idx[b] > 0);
    }
    ea[tid] = a; eb[tid] = b; ee[tid] = e; em[tid] = m;
  }
  __syncthreads();
  f32x4 acc[4][4] = {};
  for (int k0 = 0; k0 < KIN; k0 += 64) {
    #pragma unroll
    for (int p = 0; p < 4; p++) {
      int r = lrow + p * 32;
      bf16x8 v;
      if (k0 < HN) {
        bf16x8 va = *(const bf16x8*)(Sb + (size_t)ea[r] * HN + k0 + lcol);
        bf16x8 vb = *(const bf16x8*)(Sb + (size_t)eb[r] * HN + k0 + lcol);
        #pragma unroll
        for (int j = 0; j < 8; j++) v[j] = (bf16)((float)va[j] - (float)vb[j]);
      } else {
        if (em[r]) v = ld8f(noise + (size_t)ee[r] * EFN + (k0 - HN) + lcol);
        else v = zero8();
      }
      *(bf16x8*)(&As[r][lcol]) = v;
      *(bf16x8*)(&Bs[r][lcol]) = *(const bf16x8*)(W + (size_t)(bn0 + r) * KIN + k0 + lcol);
    }
    __syncthreads();
    #pragma unroll
    for (int kk = 0; kk < 2; kk++) {
      bf16x8 af[4], bfr[4];
      #pragma unroll
      for (int m = 0; m < 4; m++) af[m] = *(const bf16x8*)(&As[wm * 64 + m * 16 + lr][kk * 32 + lk * 8]);
      #pragma unroll
      for (int n = 0; n < 4; n++) bfr[n] = *(const bf16x8*)(&Bs[wn * 64 + n * 16 + lr][kk * 32 + lk * 8]);
      #pragma unroll
      for (int m = 0; m < 4; m++)
        #pragma unroll
        for (int n = 0; n < 4; n++)
          acc[m][n] = __builtin_amdgcn_mfma_f32_16x16x32_bf16(af[m], bfr[n], acc[m][n], 0, 0, 0);
    }
    __syncthreads();
  }
  #pragma unroll
  for (int n = 0; n < 4; n++) {
    int gc = bn0 + wn * 64 + n * 16 + lr;
    float bc = bias[gc];
    #pragma unroll
    for (int m = 0; m < 4; m++) {
      #pragma unroll
      for (int j = 0; j < 4; j++) {
        int gr = bm0 + wm * 64 + m * 16 + lk * 4 + j;
        if (gr < E) C[(size_t)gr * NO + gc] = (bf16)fmaxf(acc[m][n][j] + bc, 0.f);
      }
    }
  }
}

// ---------------- stage-2: msg2 * sigmoid(att2), in-place over Hmsg (BN=256) ----------------
__global__ __launch_bounds__(512) void kgemmM2(const bf16* __restrict__ Hatt, const bf16* __restrict__ Watt,
                                               const float* __restrict__ batt, bf16* __restrict__ Hmsg,
                                               const bf16* __restrict__ Wmsg, const float* __restrict__ bmsg,
                                               int E) {
  __shared__ bf16 As[128][72];
  __shared__ bf16 Bs[256][72];
  const int bm0 = blockIdx.x * 128;
  const int tid = threadIdx.x, lane = tid & 63, w = tid >> 6;
  const int wm = w >> 2, wn = w & 3, lr = lane & 15, lk = lane >> 4;
  const int lrow = tid >> 3, lcol = (tid & 7) * 8;  // lrow 0..63

  f32x4 acc_a[4][4] = {};
  for (int k0 = 0; k0 < EFN; k0 += 64) {
    #pragma unroll
    for (int p = 0; p < 2; p++) {
      int r = lrow + p * 64;
      int gr = bm0 + r;
      bf16x8 va = (gr < E) ? *(const bf16x8*)(Hatt + (size_t)gr * EFN + k0 + lcol) : zero8();
      *(bf16x8*)(&As[r][lcol]) = va;
    }
    #pragma unroll
    for (int p = 0; p < 4; p++) {
      int r = lrow + p * 64;
      *(bf16x8*)(&Bs[r][lcol]) = *(const bf16x8*)(Watt + (size_t)r * EFN + k0 + lcol);
    }
    __syncthreads();
    #pragma unroll
    for (int kk = 0; kk < 2; kk++) {
      bf16x8 af[4], bfr[4];
      #pragma unroll
      for (int m = 0; m < 4; m++) af[m] = *(const bf16x8*)(&As[wm * 64 + m * 16 + lr][kk * 32 + lk * 8]);
      #pragma unroll
      for (int n = 0; n < 4; n++) bfr[n] = *(const bf16x8*)(&Bs[wn * 64 + n * 16 + lr][kk * 32 + lk * 8]);
      #pragma unroll
      for (int m = 0; m < 4; m++)
        #pragma unroll
        for (int n = 0; n < 4; n++)
          acc_a[m][n] = __builtin_amdgcn_mfma_f32_16x16x32_bf16(af[m], bfr[n], acc_a[m][n], 0, 0, 0);
    }
    __syncthreads();
  }

  f32x4 acc_m[4][4] = {};
  for (int k0 = 0; k0 < HN; k0 += 64) {
    #pragma unroll
    for (int p = 0; p < 2; p++) {
      int r = lrow + p * 64;
      int gr = bm0 + r;
      bf16x8 va = (gr < E) ? *(const bf16x8*)(Hmsg + (size_t)gr * HN + k0 + lcol) : zero8();
      *(bf16x8*)(&As[r][lcol]) = va;
    }
    #pragma unroll
    for (int p = 0; p < 4; p++) {
      int r = lrow + p * 64;
      *(bf16x8*)(&Bs[r][lcol]) = *(const bf16x8*)(Wmsg + (size_t)r * HN + k0 + lcol);
    }
    __syncthreads();
    #pragma unroll
    for (int kk = 0; kk < 2; kk++) {
      bf16x8 af[4], bfr[4];
      #pragma unroll
      for (int m = 0; m < 4; m++) af[m] = *(const bf16x8*)(&As[wm * 64 + m * 16 + lr][kk * 32 + lk * 8]);
      #pragma unroll
      for (int n = 0; n < 4; n++) bfr[n] = *(const bf16x8*)(&Bs[wn * 64 + n * 16 + lr][kk * 32 + lk * 8]);
      #pragma unroll
      for (int m = 0; m < 4; m++)
        #pragma unroll
        for (int n = 0; n < 4; n++)
          acc_m[m][n] = __builtin_amdgcn_mfma_f32_16x16x32_bf16(af[m], bfr[n], acc_m[m][n], 0, 0, 0);
    }
    __syncthreads();
  }

  #pragma unroll
  for (int n = 0; n < 4; n++) {
    int gc = wn * 64 + n * 16 + lr;
    float bA = batt[gc], bM = bmsg[gc];
    #pragma unroll
    for (int m = 0; m < 4; m++) {
      #pragma unroll
      for (int j = 0; j < 4; j++) {
        int gr = bm0 + wm * 64 + m * 16 + lk * 4 + j;
        if (gr < E) {
          float a = sigf(acc_a[m][n][j] + bA);
          Hmsg[(size_t)gr * HN + gc] = (bf16)((acc_m[m][n][j] + bM) * a);
        }
      }
    }
  }
}

// ---------------- segment-sum over CSR ranges: aggb[n] = sum msgv rows ----------------
__global__ void kagg(const int* __restrict__ rp, const bf16* __restrict__ msgv,
                     bf16* __restrict__ aggb, int N) {
  int lane = threadIdx.x & 63;
  int gw = (blockIdx.x * blockDim.x + threadIdx.x) >> 6;
  int nw = (gridDim.x * blockDim.x) >> 6;
  for (int n = gw; n < N; n += nw) {
    int s = rp[n], t = rp[n + 1];
    f32x4 acc = {};
    for (int j = s; j < t; j++) {
      bf16x4 v = *(const bf16x4*)(msgv + (size_t)j * HN + lane * 4);
      acc[0] += (float)v[0]; acc[1] += (float)v[1]; acc[2] += (float)v[2]; acc[3] += (float)v[3];
    }
    bf16x4 o;
    o[0] = (bf16)acc[0]; o[1] = (bf16)acc[1]; o[2] = (bf16)acc[2]; o[3] = (bf16)acc[3];
    *(bf16x4*)(aggb + (size_t)n * HN + lane * 4) = o;
  }
}

// ---------------- GRU GEMM: C[M,NO](bf16) = A_bf16[M,256] @ W_bf16[NO,256]^T + bias ----------------
__global__ __launch_bounds__(256) void kgemmF(const bf16* __restrict__ A, const bf16* __restrict__ W,
                                              const float* __restrict__ bias, bf16* __restrict__ C,
                                              int M, int NO) {
  __shared__ bf16 As[128][72];
  __shared__ bf16 Bs[128][72];
  const int bm0 = blockIdx.x * 128, bn0 = blockIdx.y * 128;
  const int tid = threadIdx.x, lane = tid & 63, w = tid >> 6;
  const int wm = w >> 1, wn = w & 1, lr = lane & 15, lk = lane >> 4;
  const int lrow = tid >> 3, lcol = (tid & 7) * 8;
  f32x4 acc[4][4] = {};
  for (int k0 = 0; k0 < HN; k0 += 64) {
    #pragma unroll
    for (int p = 0; p < 4; p++) {
      int r = lrow + p * 32;
      int gr = bm0 + r;
      bf16x8 v = (gr < M) ? *(const bf16x8*)(A + (size_t)gr * HN + k0 + lcol) : zero8();
      *(bf16x8*)(&As[r][lcol]) = v;
      *(bf16x8*)(&Bs[r][lcol]) = *(const bf16x8*)(W + (size_t)(bn0 + r) * HN + k0 + lcol);
    }
    __syncthreads();
    #pragma unroll
    for (int kk = 0; kk < 2; kk++) {
      bf16x8 af[4], bfr[4];
      #pragma unroll
      for (int m = 0; m < 4; m++) af[m] = *(const bf16x8*)(&As[wm * 64 + m * 16 + lr][kk * 32 + lk * 8]);
      #pragma unroll
      for (int n = 0; n < 4; n++) bfr[n] = *(const bf16x8*)(&Bs[wn * 64 + n * 16 + lr][kk * 32 + lk * 8]);
      #pragma unroll
      for (int m = 0; m < 4; m++)
        #pragma unroll
        for (int n = 0; n < 4; n++)
          acc[m][n] = __builtin_amdgcn_mfma_f32_16x16x32_bf16(af[m], bfr[n], acc[m][n], 0, 0, 0);
    }
    __syncthreads();
  }
  #pragma unroll
  for (int n = 0; n < 4; n++) {
    int gc = bn0 + wn * 64 + n * 16 + lr;
    float bc = bias[gc];
    #pragma unroll
    for (int m = 0; m < 4; m++) {
      #pragma unroll
      for (int j = 0; j < 4; j++) {
        int gr = bm0 + wm * 64 + m * 16 + lk * 4 + j;
        if (gr < M) C[(size_t)gr * NO + gc] = (bf16)(acc[m][n][j] + bc);
      }
    }
  }
}

// ---------------- head GEMM-1 with fused pair-diff gather (bf16 state) ----------------
__global__ __launch_bounds__(256) void kgemmP(const int* __restrict__ pidx, const bf16* __restrict__ Sb,
                                              const bf16* __restrict__ W, const float* __restrict__ bias,
                                              bf16* __restrict__ C, int M, int NO) {
  __shared__ bf16 As[128][72];
  __shared__ bf16 Bs[128][72];
  __shared__ int ia[128], ib[128];
  const int bm0 = blockIdx.x * 128, bn0 = blockIdx.y * 128;
  const int tid = threadIdx.x, lane = tid & 63, w = tid >> 6;
  const int wm = w >> 1, wn = w & 1, lr = lane & 15, lk = lane >> 4;
  const int lrow = tid >> 3, lcol = (tid & 7) * 8;
  if (tid < 128) {
    int p = bm0 + tid;
    int a = 0, b = 0;
    if (p < M) { a = pidx[2 * p]; b = pidx[2 * p + 1]; }
    ia[tid] = a; ib[tid] = b;
  }
  __syncthreads();
  f32x4 acc[4][4] = {};
  for (int k0 = 0; k0 < HN; k0 += 64) {
    #pragma unroll
    for (int p = 0; p < 4; p++) {
      int r = lrow + p * 32;
      bf16x8 va = *(const bf16x8*)(Sb + (size_t)ia[r] * HN + k0 + lcol);
      bf16x8 vb = *(const bf16x8*)(Sb + (size_t)ib[r] * HN + k0 + lcol);
      bf16x8 v;
      #pragma unroll
      for (int j = 0; j < 8; j++) v[j] = (bf16)((float)va[j] - (float)vb[j]);
      *(bf16x8*)(&As[r][lcol]) = v;
      *(bf16x8*)(&Bs[r][lcol]) = *(const bf16x8*)(W + (size_t)(bn0 + r) * HN + k0 + lcol);
    }
    __syncthreads();
    #pragma unroll
    for (int kk = 0; kk < 2; kk++) {
      bf16x8 af[4], bfr[4];
      #pragma unroll
      for (int m = 0; m < 4; m++) af[m] = *(const bf16x8*)(&As[wm * 64 + m * 16 + lr][kk * 32 + lk * 8]);
      #pragma unroll
      for (int n = 0; n < 4; n++) bfr[n] = *(const bf16x8*)(&Bs[wn * 64 + n * 16 + lr][kk * 32 + lk * 8]);
      #pragma unroll
      for (int m = 0; m < 4; m++)
        #pragma unroll
        for (int n = 0; n < 4; n++)
          acc[m][n] = __builtin_amdgcn_mfma_f32_16x16x32_bf16(af[m], bfr[n], acc[m][n], 0, 0, 0);
    }
    __syncthreads();
  }
  #pragma unroll
  for (int n = 0; n < 4; n++) {
    int gc = bn0 + wn * 64 + n * 16 + lr;
    float bc = bias[gc];
    #pragma unroll
    for (int m = 0; m < 4; m++) {
      #pragma unroll
      for (int j = 0; j < 4; j++) {
        int gr = bm0 + wm * 64 + m * 16 + lk * 4 + j;
        if (gr < M) C[(size_t)gr * NO + gc] = (bf16)fmaxf(acc[m][n][j] + bc, 0.f);
      }
    }
  }
}

// ---------------- head GEMM-2: bf16 A, bf16 W, relu ----------------
__global__ __launch_bounds__(256) void kgemmB(const bf16* __restrict__ A, const bf16* __restrict__ W,
                                              const float* __restrict__ bias, bf16* __restrict__ C,
                                              int M, int NO) {
  __shared__ bf16 As[128][72];
  __shared__ bf16 Bs[128][72];
  const int bm0 = blockIdx.x * 128, bn0 = blockIdx.y * 128;
  const int tid = threadIdx.x, lane = tid & 63, w = tid >> 6;
  const int wm = w >> 1, wn = w & 1, lr = lane & 15, lk = lane >> 4;
  const int lrow = tid >> 3, lcol = (tid & 7) * 8;
  f32x4 acc[4][4] = {};
  for (int k0 = 0; k0 < HN; k0 += 64) {
    #pragma unroll
    for (int p = 0; p < 4; p++) {
      int r = lrow + p * 32;
      int gr = bm0 + r;
      bf16x8 v = (gr < M) ? *(const bf16x8*)(A + (size_t)gr * HN + k0 + lcol) : zero8();
      *(bf16x8*)(&As[r][lcol]) = v;
      *(bf16x8*)(&Bs[r][lcol]) = *(const bf16x8*)(W + (size_t)(bn0 + r) * HN + k0 + lcol);
    }
    __syncthreads();
    #pragma unroll
    for (int kk = 0; kk < 2; kk++) {
      bf16x8 af[4], bfr[4];
      #pragma unroll
      for (int m = 0; m < 4; m++) af[m] = *(const bf16x8*)(&As[wm * 64 + m * 16 + lr][kk * 32 + lk * 8]);
      #pragma unroll
      for (int n = 0; n < 4; n++) bfr[n] = *(const bf16x8*)(&Bs[wn * 64 + n * 16 + lr][kk * 32 + lk * 8]);
      #pragma unroll
      for (int m = 0; m < 4; m++)
        #pragma unroll
        for (int n = 0; n < 4; n++)
          acc[m][n] = __builtin_amdgcn_mfma_f32_16x16x32_bf16(af[m], bfr[n], acc[m][n], 0, 0, 0);
    }
    __syncthreads();
  }
  #pragma unroll
  for (int n = 0; n < 4; n++) {
    int gc = bn0 + wn * 64 + n * 16 + lr;
    float bc = bias[gc];
    #pragma unroll
    for (int m = 0; m < 4; m++) {
      #pragma unroll
      for (int j = 0; j < 4; j++) {
        int gr = bm0 + wm * 64 + m * 16 + lk * 4 + j;
        if (gr < M) C[(size_t)gr * NO + gc] = (bf16)fmaxf(acc[m][n][j] + bc, 0.f);
      }
    }
  }
}

// ---------------- GRU gate (updates f32 master S and bf16 mirror Sb) ----------------
__global__ void kgate(const bf16* __restrict__ gi, const bf16* __restrict__ gh,
                      float* __restrict__ S, bf16* __restrict__ Sb, int n, int dorelu) {
  int total = n * 32;
  for (int id = blockIdx.x * blockDim.x + threadIdx.x; id < total; id += gridDim.x * blockDim.x) {
    int i = id >> 5;
    int h = (id & 31) * 8;
    const bf16* pgi = gi + (size_t)i * G3 + h;
    const bf16* pgh = gh + (size_t)i * G3 + h;
    bf16x8 gr8 = *(const bf16x8*)(pgi);
    bf16x8 hr8 = *(const bf16x8*)(pgh);
    bf16x8 gz8 = *(const bf16x8*)(pgi + HN);
    bf16x8 hz8 = *(const bf16x8*)(pgh + HN);
    bf16x8 gn8 = *(const bf16x8*)(pgi + 2 * HN);
    bf16x8 hn8 = *(const bf16x8*)(pgh + 2 * HN);
    float* ps = S + (size_t)i * HN + h;
    f32x4 h0 = *(const f32x4*)ps;
    f32x4 h1 = *(const f32x4*)(ps + 4);
    f32x4 o0, o1;
    bf16x8 ob;
    #pragma unroll
    for (int j = 0; j < 8; j++) {
      float hv = (j < 4) ? h0[j] : h1[j - 4];
      float r = sigf((float)gr8[j] + (float)hr8[j]);
      float z = sigf((float)gz8[j] + (float)hz8[j]);
      float nn = tanhf((float)gn8[j] + r * (float)hn8[j]);
      float s = (1.f - z) * nn + z * hv;
      if (dorelu) s = fmaxf(s, 0.f);
      if (j < 4) o0[j] = s; else o1[j - 4] = s;
      ob[j] = (bf16)s;
    }
    *(f32x4*)ps = o0;
    *(f32x4*)(ps + 4) = o1;
    *(bf16x8*)(Sb + (size_t)i * HN + h) = ob;
  }
}

// ---------------- final 20-col head ----------------
__global__ __launch_bounds__(256) void khead_out(const bf16* __restrict__ Hb, const float* __restrict__ W,
                                                 const float* __restrict__ bias, float* __restrict__ out, int P) {
  __shared__ float Wl[KMIXN][256];
  __shared__ float bl[KMIXN];
  for (int i = threadIdx.x; i < KMIXN * 256; i += 256) Wl[i >> 8][i & 255] = W[i];
  if (threadIdx.x < KMIXN) bl[threadIdx.x] = bias[threadIdx.x];
  __syncthreads();
  int lane = threadIdx.x & 63;
  int wv = threadIdx.x >> 6;
  for (int p = blockIdx.x * 4 + wv; p < P; p += gridDim.x * 4) {
    bf16x4 hv = *(const bf16x4*)(Hb + (size_t)p * HN + lane * 4);
    float h0 = (float)hv[0], h1 = (float)hv[1], h2 = (float)hv[2], h3 = (float)hv[3];
    float pk[KMIXN];
    #pragma unroll
    for (int k = 0; k < KMIXN; k++) {
      const float* wr = &Wl[k][lane * 4];
      pk[k] = h0 * wr[0] + h1 * wr[1] + h2 * wr[2] + h3 * wr[3];
    }
    #pragma unroll
    for (int k = 0; k < KMIXN; k++)
      #pragma unroll
      for (int o = 32; o > 0; o >>= 1) pk[k] += __shfl_down(pk[k], o, 64);
    if (lane == 0) {
      #pragma unroll
      for (int k = 0; k < KMIXN; k++) out[(size_t)p * KMIXN + k] = pk[k] + bl[k];
    }
  }
}

static inline size_t alup(size_t x) { return (x + 255) & ~(size_t)255; }

extern "C" void kernel_launch(void* const* d_in, const int* in_sizes, int n_in,
                              void* d_out, int out_size, void* d_ws, size_t ws_size,
                              hipStream_t stream) {
  const int* user_idx = (const int*)d_in[0];
  const int* node_idx_feat = (const int*)d_in[1];
  const float* pos_flag = (const float*)d_in[2];
  const int* edges = (const int*)d_in[3];
  const int* node_idx_gnn = (const int*)d_in[4];
  const int* att_idx = (const int*)d_in[5];
  const float* att_noise = (const float*)d_in[6];
  const float* users = (const float*)d_in[7];
  const float* items = (const float*)d_in[8];
  const float* msg_w1 = (const float*)d_in[9];
  const float* msg_b1 = (const float*)d_in[10];
  const float* msg_w2 = (const float*)d_in[11];
  const float* msg_b2 = (const float*)d_in[12];
  const float* att_w1 = (const float*)d_in[13];
  const float* att_b1 = (const float*)d_in[14];
  const float* att_w2 = (const float*)d_in[15];
  const float* att_b2 = (const float*)d_in[16];
  const float* gru_wih = (const float*)d_in[17];
  const float* gru_bih = (const float*)d_in[18];
  const float* gru_whh = (const float*)d_in[19];
  const float* gru_bhh = (const float*)d_in[20];
  const float* theta_w1 = (const float*)d_in[21];
  const float* theta_b1 = (const float*)d_in[22];
  const float* theta_w2 = (const float*)d_in[23];
  const float* theta_b2 = (const float*)d_in[24];
  const float* theta_w3 = (const float*)d_in[25];
  const float* theta_b3 = (const float*)d_in[26];
  const float* alpha_w1 = (const float*)d_in[27];
  const float* alpha_b1 = (const float*)d_in[28];
  const float* alpha_w2 = (const float*)d_in[29];
  const float* alpha_b2 = (const float*)d_in[30];
  const float* alpha_w3 = (const float*)d_in[31];
  const float* alpha_b3 = (const float*)d_in[32];

  const int N = in_sizes[0];
  const int E = in_sizes[3] / 2;
  const int P = in_sizes[4] / 2;

  float* out_theta = (float*)d_out;
  float* out_alpha = out_theta + (size_t)P * KMIXN;
  float* out_bpr = out_theta + 2 * (size_t)P * KMIXN;

  // ---- workspace carve (~236 MB) ----
  char* ws = (char*)d_ws;
  size_t off = 0;
  float* S = (float*)(ws + off); off += alup((size_t)N * HN * 4);
  bf16* Sb = (bf16*)(ws + off); off += alup((size_t)N * HN * 2);
  // weights bf16 (10 arrays)
  const int L2N = 2;
  int wc[11];
  wc[0] = 0;
  wc[1] = wc[0] + L2N * HN * KIN;   // msg_w1
  wc[2] = wc[1] + L2N * EFN * KIN;  // att_w1
  wc[3] = wc[2] + L2N * HN * HN;    // msg_w2
  wc[4] = wc[3] + L2N * HN * EFN;   // att_w2
  wc[5] = wc[4] + L2N * G3 * HN;    // gru_wih
  wc[6] = wc[5] + L2N * G3 * HN;    // gru_whh
  wc[7] = wc[6] + HN * HN;          // theta_w1
  wc[8] = wc[7] + HN * HN;          // theta_w2
  wc[9] = wc[8] + HN * HN;          // alpha_w1
  wc[10] = wc[9] + HN * HN;         // alpha_w2
  bf16* wb = (bf16*)(ws + off); off += alup((size_t)wc[10] * 2);
  bf16* wb_m1 = wb + wc[0];
  bf16* wb_a1 = wb + wc[1];
  bf16* wb_m2 = wb + wc[2];
  bf16* wb_a2 = wb + wc[3];
  bf16* wb_gih = wb + wc[4];
  bf16* wb_ghh = wb + wc[5];
  bf16* wb_tw1 = wb + wc[6];
  bf16* wb_tw2 = wb + wc[7];
  bf16* wb_aw1 = wb + wc[8];
  bf16* wb_aw2 = wb + wc[9];
  int* rp = (int*)(ws + off); off += alup((size_t)(N + 1) * 4);
  int* cur = (int*)(ws + off); off += alup((size_t)N * 4);
  int* csrA = (int*)(ws + off); off += alup((size_t)E * 4);
  int* csrB = (int*)(ws + off); off += alup((size_t)E * 4);
  int* csrE = (int*)(ws + off); off += alup((size_t)E * 4);
  float* scal = (float*)(ws + off); off += 256;
  char* X1 = ws + off;
  size_t szHm = (size_t)E * HN * 2;     // 102.4 MB
  size_t szGIb = (size_t)N * G3 * 2;    // 76.8 MB
  bf16* Hmsg = (bf16*)X1;
  bf16* Hatt = (bf16*)(X1 + szHm);
  bf16* aggb = (bf16*)(X1 + szHm);      // aliases Hatt (dead by then)
  bf16* gi = (bf16*)X1;                 // over dead msgv
  bf16* gh = (bf16*)(X1 + szGIb);
  int PC = (P + 1) / 2;
  size_t szH1 = (size_t)PC * HN * 2;    // 51.2 MB
  bf16* h1 = (bf16*)X1;
  bf16* h2 = (bf16*)(X1 + szH1);

  const int gE = (E + 127) / 128;
  const int gN = (N + 127) / 128;

  // ---- prep: CSR + weight conversion + scalars ----
  hipMemsetAsync(rp, 0, (size_t)(N + 1) * 4, stream);
  hipMemsetAsync(scal, 0, 4, stream);
  kdeg<<<512, 256, 0, stream>>>(edges, rp, E);
  kscan<<<1, 1024, 0, stream>>>(rp, N);
  kcpy<<<64, 256, 0, stream>>>(rp, cur, N);
  kfill<<<512, 256, 0, stream>>>(edges, cur, csrA, csrB, csrE, E);
  WList wl;
  wl.s[0] = msg_w1; wl.s[1] = att_w1; wl.s[2] = msg_w2; wl.s[3] = att_w2;
  wl.s[4] = gru_wih; wl.s[5] = gru_whh; wl.s[6] = theta_w1; wl.s[7] = theta_w2;
  wl.s[8] = alpha_w1; wl.s[9] = alpha_w2;
  for (int i = 0; i < 11; i++) wl.c[i] = wc[i];
  kwcvt<<<1024, 256, 0, stream>>>(wl, wb);
  ksum<<<256, 256, 0, stream>>>(pos_flag, N, scal);
  kinit<<<1024, 256, 0, stream>>>(user_idx, node_idx_feat, pos_flag, users, items, S, Sb, out_bpr, scal, N);

  for (int li = 0; li < 2; li++) {
    kgemmE<<<dim3(gE, 3), 256, 0, stream>>>(csrA, csrB, csrE, att_idx, att_noise, Sb,
                                            wb_m1 + (size_t)li * HN * KIN, msg_b1 + li * HN,
                                            wb_a1 + (size_t)li * EFN * KIN, att_b1 + li * EFN,
                                            Hmsg, Hatt, E);
    kgemmM2<<<dim3(gE, 1), 512, 0, stream>>>(Hatt, wb_a2 + (size_t)li * HN * EFN, att_b2 + li * HN,
                                             Hmsg, wb_m2 + (size_t)li * HN * HN, msg_b2 + li * HN, E);
    kagg<<<1024, 256, 0, stream>>>(rp, Hmsg, aggb, N);
    kgemmF<<<dim3(gN, 6), 256, 0, stream>>>(aggb, wb_gih + (size_t)li * G3 * HN, gru_bih + li * G3, gi, N, G3);
    kgemmF<<<dim3(gN, 6), 256, 0, stream>>>(Sb, wb_ghh + (size_t)li * G3 * HN, gru_bhh + li * G3, gh, N, G3);
    kgate<<<2048, 256, 0, stream>>>(gi, gh, S, Sb, N, li == 0 ? 1 : 0);
  }

  // heads, chunked over P
  for (int c = 0; c < 2; c++) {
    int pc0 = c * PC;
    int pcn = (P - pc0 < PC) ? (P - pc0) : PC;
    if (pcn <= 0) break;
    int gPc = (pcn + 127) / 128;
    kgemmP<<<dim3(gPc, 2), 256, 0, stream>>>(node_idx_gnn + (size_t)pc0 * 2, Sb, wb_tw1, theta_b1, h1, pcn, HN);
    kgemmB<<<dim3(gPc, 2), 256, 0, stream>>>(h1, wb_tw2, theta_b2, h2, pcn, HN);
    khead_out<<<4096, 256, 0, stream>>>(h2, theta_w3, theta_b3, out_theta + (size_t)pc0 * KMIXN, pcn);
    kgemmP<<<dim3(gPc, 2), 256, 0, stream>>>(node_idx_gnn + (size_t)pc0 * 2, Sb, wb_aw1, alpha_b1, h1, pcn, HN);
    kgemmB<<<dim3(gPc, 2), 256, 0, stream>>>(h1, wb_aw2, alpha_b2, h2, pcn, HN);
    khead_out<<<4096, 256, 0, stream>>>(h2, alpha_w3, alpha_b3, out_alpha + (size_t)pc0 * KMIXN, pcn);
  }
}

// Round 5
// 2173.890 us; speedup vs baseline: 1.4503x; 1.2544x over previous
//
#include <hip/hip_runtime.h>
#include <math.h>

typedef __bf16 bf16;
typedef __bf16 bf16x8 __attribute__((ext_vector_type(8)));
typedef __bf16 bf16x4 __attribute__((ext_vector_type(4)));
typedef float f32x4 __attribute__((ext_vector_type(4)));

#define HN 256
#define EFN 128
#define KIN 384
#define G3 768
#define KMIXN 20

__device__ __forceinline__ float sigf(float x) { return 1.0f / (1.0f + __expf(-x)); }

__device__ __forceinline__ bf16x8 ld8f(const float* __restrict__ p) {
  f32x4 a = *(const f32x4*)p, b = *(const f32x4*)(p + 4);
  bf16x8 v;
  v[0] = (bf16)a[0]; v[1] = (bf16)a[1]; v[2] = (bf16)a[2]; v[3] = (bf16)a[3];
  v[4] = (bf16)b[0]; v[5] = (bf16)b[1]; v[6] = (bf16)b[2]; v[7] = (bf16)b[3];
  return v;
}
__device__ __forceinline__ bf16x8 zero8() {
  bf16x8 v; bf16 z = (bf16)0.f;
  v[0]=z;v[1]=z;v[2]=z;v[3]=z;v[4]=z;v[5]=z;v[6]=z;v[7]=z; return v;
}

// coalesced epilogue for a 64x64 wave tile: LDS transpose then 16B/lane row stores
template <int ACT>
__device__ __forceinline__ void epi_store64(f32x4 (&acc)[4][4], bf16* smw,
                                            const float* __restrict__ bias, int colbase,
                                            bf16* __restrict__ C, int stride,
                                            int rowbase, int M, int lane) {
  const int lr = lane & 15, lk = lane >> 4;
  const int row = lane >> 2, q = lane & 3;
  float bc[4];
  #pragma unroll
  for (int n = 0; n < 4; n++) bc[n] = bias[colbase + n * 16 + lr];
  #pragma unroll
  for (int m = 0; m < 4; m++) {
    #pragma unroll
    for (int n = 0; n < 4; n++) {
      #pragma unroll
      for (int j = 0; j < 4; j++) {
        float v = acc[m][n][j] + bc[n];
        if (ACT) v = fmaxf(v, 0.f);
        smw[(lk * 4 + j) * 72 + n * 16 + lr] = (bf16)v;
      }
    }
    __syncthreads();
    bf16x8 v0 = *(const bf16x8*)(smw + row * 72 + q * 16);
    bf16x8 v1 = *(const bf16x8*)(smw + row * 72 + q * 16 + 8);
    int gr = rowbase + m * 16 + row;
    if (gr < M) {
      bf16* dst = C + (size_t)gr * stride + colbase + q * 16;
      *(bf16x8*)dst = v0;
      *(bf16x8*)(dst + 8) = v1;
    }
    __syncthreads();
  }
}

// ---------------- weight f32->bf16 ----------------
struct WList { const float* s[10]; int c[11]; };
__global__ void kwcvt(WList wl, bf16* __restrict__ wb) {
  int total = wl.c[10];
  for (int id = blockIdx.x * blockDim.x + threadIdx.x; id < total; id += gridDim.x * blockDim.x) {
    int i = 0;
    #pragma unroll
    for (int k = 1; k < 10; k++) if (id >= wl.c[k]) i = k;
    wb[id] = (bf16)wl.s[i][id - wl.c[i]];
  }
}

// ---------------- CSR build ----------------
__global__ void kdeg(const int* __restrict__ edges, int* __restrict__ rp, int E) {
  for (int e = blockIdx.x * blockDim.x + threadIdx.x; e < E; e += gridDim.x * blockDim.x)
    atomicAdd(&rp[edges[2 * e + 1] + 1], 1);
}
__global__ void kscan(int* __restrict__ rp, int n) {
  __shared__ int buf[1024];
  __shared__ int carry;
  if (threadIdx.x == 0) carry = 0;
  __syncthreads();
  for (int base = 1; base <= n; base += 1024) {
    int i = base + threadIdx.x;
    int v = (i <= n) ? rp[i] : 0;
    buf[threadIdx.x] = v;
    __syncthreads();
    for (int o = 1; o < 1024; o <<= 1) {
      int t = (threadIdx.x >= o) ? buf[threadIdx.x - o] : 0;
      __syncthreads();
      buf[threadIdx.x] += t;
      __syncthreads();
    }
    if (i <= n) rp[i] = buf[threadIdx.x] + carry;
    __syncthreads();
    if (threadIdx.x == 0) carry += buf[1023];
    __syncthreads();
  }
}
__global__ void kcpy(const int* __restrict__ rp, int* __restrict__ cur, int n) {
  for (int i = blockIdx.x * blockDim.x + threadIdx.x; i < n; i += gridDim.x * blockDim.x)
    cur[i] = rp[i];
}
__global__ void kfill(const int* __restrict__ edges, int* __restrict__ cur,
                      int* __restrict__ csrA, int* __restrict__ csrB, int* __restrict__ csrE, int E) {
  for (int e = blockIdx.x * blockDim.x + threadIdx.x; e < E; e += gridDim.x * blockDim.x) {
    int a = edges[2 * e], b = edges[2 * e + 1];
    int p = atomicAdd(&cur[b], 1);
    csrA[p] = a; csrB[p] = b; csrE[p] = e;
  }
}

// ---------------- flag sum ----------------
__global__ void ksum(const float* __restrict__ flags, int n, float* __restrict__ scal) {
  __shared__ float red[4];
  float s = 0.f;
  for (int i = blockIdx.x * blockDim.x + threadIdx.x; i < n; i += gridDim.x * blockDim.x)
    s += flags[i];
  #pragma unroll
  for (int o = 32; o > 0; o >>= 1) s += __shfl_down(s, o, 64);
  int lane = threadIdx.x & 63, w = threadIdx.x >> 6;
  if (lane == 0) red[w] = s;
  __syncthreads();
  if (threadIdx.x == 0) atomicAdd(scal, red[0] + red[1] + red[2] + red[3]);
}

// ---------------- state init + bpr (bf16 state only) ----------------
__global__ void kinit(const int* __restrict__ user_idx, const int* __restrict__ node_idx_feat,
                      const float* __restrict__ flags, const float* __restrict__ users,
                      const float* __restrict__ items, bf16* __restrict__ Sb,
                      float* __restrict__ bpr_out, const float* __restrict__ scal, int n) {
  int lane = threadIdx.x & 63;
  int gw = (blockIdx.x * blockDim.x + threadIdx.x) >> 6;
  int nw = (gridDim.x * blockDim.x) >> 6;
  float sp = scal[0];
  float sn = (float)n - sp;
  for (int i = gw; i < n; i += nw) {
    int u = user_idx[i], it = node_idx_feat[i];
    f32x4 uv = *(const f32x4*)(users + (size_t)u * HN + lane * 4);
    f32x4 iv = *(const f32x4*)(items + (size_t)it * HN + lane * 4);
    bf16x4 ib;
    ib[0] = (bf16)iv[0]; ib[1] = (bf16)iv[1]; ib[2] = (bf16)iv[2]; ib[3] = (bf16)iv[3];
    *(bf16x4*)(Sb + (size_t)i * HN + lane * 4) = ib;
    float d = uv[0] * iv[0] + uv[1] * iv[1] + uv[2] * iv[2] + uv[3] * iv[3];
    #pragma unroll
    for (int o = 32; o > 0; o >>= 1) d += __shfl_down(d, o, 64);
    if (lane == 0) {
      float f = flags[i];
      float x = (1.f - f) * d / sn - f * d / sp;
      float b = (x > 20.f) ? x : log1pf(expf(x));
      bpr_out[i] = b;
    }
  }
}

// ---------------- stage-1: merged msg1+att1 GEMM, fused gather, one pass ----------------
// Hall[e][0:256] = relu(edge_in @ Wm^T + bm), Hall[e][256:384] = relu(edge_in @ Wa^T + ba)
__global__ __launch_bounds__(512) void kgemmE(const int* __restrict__ csrA, const int* __restrict__ csrB,
                                              const int* __restrict__ csrE, const int* __restrict__ att_idx,
                                              const float* __restrict__ noise, const bf16* __restrict__ Sb,
                                              const bf16* __restrict__ Wm, const float* __restrict__ bm,
                                              const bf16* __restrict__ Wa, const float* __restrict__ ba,
                                              bf16* __restrict__ Hall, int E) {
  __shared__ bf16 sm[36864];           // As[128][72] | Bs[384][72]; epilogue aliases
  __shared__ int ea[128], eb[128], ee[128];
  __shared__ unsigned char em[128];
  bf16* As = sm;
  bf16* Bs = sm + 128 * 72;
  const int bm0 = blockIdx.x * 128;
  const int tid = threadIdx.x, lane = tid & 63, w = tid >> 6;
  const int wm = w >> 2, wn = w & 3, lr = lane & 15, lk = lane >> 4;
  const int lrow = tid >> 3, lcol = (tid & 7) * 8;
  if (tid < 128) {
    int p = bm0 + tid;
    int a = 0, b = 0, e = 0; unsigned char m = 0;
    if (p < E) {
      a = csrA[p]; b = csrB[p]; e = csrE[p];
      m = (att_idx[a] > 0) || (att_idx[b] > 0);
    }
    ea[tid] = a; eb[tid] = b; ee[tid] = e; em[tid] = m;
  }
  __syncthreads();
  f32x4 acc[4][6] = {};
  for (int k0 = 0; k0 < KIN; k0 += 64) {
    #pragma unroll
    for (int p = 0; p < 2; p++) {
      int r = lrow + p * 64;
      bf16x8 v;
      if (k0 < HN) {
        bf16x8 va = *(const bf16x8*)(Sb + (size_t)ea[r] * HN + k0 + lcol);
        bf16x8 vb = *(const bf16x8*)(Sb + (size_t)eb[r] * HN + k0 + lcol);
        #pragma unroll
        for (int j = 0; j < 8; j++) v[j] = (bf16)((float)va[j] - (float)vb[j]);
      } else {
        if (em[r]) v = ld8f(noise + (size_t)ee[r] * EFN + (k0 - HN) + lcol);
        else v = zero8();
      }
      *(bf16x8*)(&As[r * 72 + lcol]) = v;
    }
    #pragma unroll
    for (int p = 0; p < 6; p++) {
      int r = lrow + p * 64;
      const bf16* wp = (p < 4) ? (Wm + (size_t)r * KIN) : (Wa + (size_t)(r - 256) * KIN);
      *(bf16x8*)(&Bs[r * 72 + lcol]) = *(const bf16x8*)(wp + k0 + lcol);
    }
    __syncthreads();
    #pragma unroll
    for (int kk = 0; kk < 2; kk++) {
      bf16x8 af[4], bfr[6];
      #pragma unroll
      for (int m = 0; m < 4; m++) af[m] = *(const bf16x8*)(&As[(wm * 64 + m * 16 + lr) * 72 + kk * 32 + lk * 8]);
      #pragma unroll
      for (int n = 0; n < 6; n++) bfr[n] = *(const bf16x8*)(&Bs[(wn * 96 + n * 16 + lr) * 72 + kk * 32 + lk * 8]);
      #pragma unroll
      for (int m = 0; m < 4; m++)
        #pragma unroll
        for (int n = 0; n < 6; n++)
          acc[m][n] = __builtin_amdgcn_mfma_f32_16x16x32_bf16(af[m], bfr[n], acc[m][n], 0, 0, 0);
    }
    __syncthreads();
  }
  // epilogue: LDS transpose, coalesced 384-wide rows
  float bc[6];
  #pragma unroll
  for (int n = 0; n < 6; n++) {
    int gc = wn * 96 + n * 16 + lr;
    bc[n] = (gc < HN) ? bm[gc] : ba[gc - HN];
  }
  bf16* smw = sm + w * 1664;  // 16 x 104 per wave
  const int row = lane >> 2, q = lane & 3;
  #pragma unroll
  for (int m = 0; m < 4; m++) {
    #pragma unroll
    for (int n = 0; n < 6; n++)
      #pragma unroll
      for (int j = 0; j < 4; j++)
        smw[(lk * 4 + j) * 104 + n * 16 + lr] = (bf16)fmaxf(acc[m][n][j] + bc[n], 0.f);
    __syncthreads();
    const bf16* ep = smw + row * 104 + q * 24;
    bf16x8 v0 = *(const bf16x8*)ep;
    bf16x8 v1 = *(const bf16x8*)(ep + 8);
    bf16x8 v2 = *(const bf16x8*)(ep + 16);
    int gr = bm0 + wm * 64 + m * 16 + row;
    if (gr < E) {
      bf16* dst = Hall + (size_t)gr * KIN + wn * 96 + q * 24;
      *(bf16x8*)dst = v0; *(bf16x8*)(dst + 8) = v1; *(bf16x8*)(dst + 16) = v2;
    }
    __syncthreads();
  }
}

// ---------------- stage-2: msg2 * sigmoid(att2), in-place over Hall[:,0:256] ----------------
__global__ __launch_bounds__(512) void kgemmM2(bf16* __restrict__ Hall, const bf16* __restrict__ Watt,
                                               const float* __restrict__ batt,
                                               const bf16* __restrict__ Wmsg, const float* __restrict__ bmsg,
                                               int E) {
  __shared__ bf16 sm[27648];  // As[128][72] | Bs[256][72]
  bf16* As = sm;
  bf16* Bs = sm + 128 * 72;
  const int bm0 = blockIdx.x * 128;
  const int tid = threadIdx.x, lane = tid & 63, w = tid >> 6;
  const int wm = w >> 2, wn = w & 3, lr = lane & 15, lk = lane >> 4;
  const int lrow = tid >> 3, lcol = (tid & 7) * 8;

  f32x4 acc_a[4][4] = {};
  for (int k0 = 0; k0 < EFN; k0 += 64) {
    #pragma unroll
    for (int p = 0; p < 2; p++) {
      int r = lrow + p * 64;
      int gr = bm0 + r;
      bf16x8 va = (gr < E) ? *(const bf16x8*)(Hall + (size_t)gr * KIN + HN + k0 + lcol) : zero8();
      *(bf16x8*)(&As[r * 72 + lcol]) = va;
    }
    #pragma unroll
    for (int p = 0; p < 4; p++) {
      int r = lrow + p * 64;
      *(bf16x8*)(&Bs[r * 72 + lcol]) = *(const bf16x8*)(Watt + (size_t)r * EFN + k0 + lcol);
    }
    __syncthreads();
    #pragma unroll
    for (int kk = 0; kk < 2; kk++) {
      bf16x8 af[4], bfr[4];
      #pragma unroll
      for (int m = 0; m < 4; m++) af[m] = *(const bf16x8*)(&As[(wm * 64 + m * 16 + lr) * 72 + kk * 32 + lk * 8]);
      #pragma unroll
      for (int n = 0; n < 4; n++) bfr[n] = *(const bf16x8*)(&Bs[(wn * 64 + n * 16 + lr) * 72 + kk * 32 + lk * 8]);
      #pragma unroll
      for (int m = 0; m < 4; m++)
        #pragma unroll
        for (int n = 0; n < 4; n++)
          acc_a[m][n] = __builtin_amdgcn_mfma_f32_16x16x32_bf16(af[m], bfr[n], acc_a[m][n], 0, 0, 0);
    }
    __syncthreads();
  }

  f32x4 acc_m[4][4] = {};
  for (int k0 = 0; k0 < HN; k0 += 64) {
    #pragma unroll
    for (int p = 0; p < 2; p++) {
      int r = lrow + p * 64;
      int gr = bm0 + r;
      bf16x8 va = (gr < E) ? *(const bf16x8*)(Hall + (size_t)gr * KIN + k0 + lcol) : zero8();
      *(bf16x8*)(&As[r * 72 + lcol]) = va;
    }
    #pragma unroll
    for (int p = 0; p < 4; p++) {
      int r = lrow + p * 64;
      *(bf16x8*)(&Bs[r * 72 + lcol]) = *(const bf16x8*)(Wmsg + (size_t)r * HN + k0 + lcol);
    }
    __syncthreads();
    #pragma unroll
    for (int kk = 0; kk < 2; kk++) {
      bf16x8 af[4], bfr[4];
      #pragma unroll
      for (int m = 0; m < 4; m++) af[m] = *(const bf16x8*)(&As[(wm * 64 + m * 16 + lr) * 72 + kk * 32 + lk * 8]);
      #pragma unroll
      for (int n = 0; n < 4; n++) bfr[n] = *(const bf16x8*)(&Bs[(wn * 64 + n * 16 + lr) * 72 + kk * 32 + lk * 8]);
      #pragma unroll
      for (int m = 0; m < 4; m++)
        #pragma unroll
        for (int n = 0; n < 4; n++)
          acc_m[m][n] = __builtin_amdgcn_mfma_f32_16x16x32_bf16(af[m], bfr[n], acc_m[m][n], 0, 0, 0);
    }
    __syncthreads();
  }

  float bA[4], bM[4];
  #pragma unroll
  for (int n = 0; n < 4; n++) {
    int gc = wn * 64 + n * 16 + lr;
    bA[n] = batt[gc]; bM[n] = bmsg[gc];
  }
  bf16* smw = sm + w * 1152;
  const int row = lane >> 2, q = lane & 3;
  #pragma unroll
  for (int m = 0; m < 4; m++) {
    #pragma unroll
    for (int n = 0; n < 4; n++)
      #pragma unroll
      for (int j = 0; j < 4; j++) {
        float a = sigf(acc_a[m][n][j] + bA[n]);
        smw[(lk * 4 + j) * 72 + n * 16 + lr] = (bf16)((acc_m[m][n][j] + bM[n]) * a);
      }
    __syncthreads();
    bf16x8 v0 = *(const bf16x8*)(smw + row * 72 + q * 16);
    bf16x8 v1 = *(const bf16x8*)(smw + row * 72 + q * 16 + 8);
    int gr = bm0 + wm * 64 + m * 16 + row;
    if (gr < E) {
      bf16* dst = Hall + (size_t)gr * KIN + wn * 64 + q * 16;
      *(bf16x8*)dst = v0; *(bf16x8*)(dst + 8) = v1;
    }
    __syncthreads();
  }
}

// ---------------- segment-sum over CSR ranges (stride-384 msg rows) ----------------
__global__ void kagg(const int* __restrict__ rp, const bf16* __restrict__ Hall,
                     bf16* __restrict__ aggb, int N) {
  int lane = threadIdx.x & 63;
  int gw = (blockIdx.x * blockDim.x + threadIdx.x) >> 6;
  int nw = (gridDim.x * blockDim.x) >> 6;
  for (int n = gw; n < N; n += nw) {
    int s = rp[n], t = rp[n + 1];
    f32x4 acc = {};
    for (int j = s; j < t; j++) {
      bf16x4 v = *(const bf16x4*)(Hall + (size_t)j * KIN + lane * 4);
      acc[0] += (float)v[0]; acc[1] += (float)v[1]; acc[2] += (float)v[2]; acc[3] += (float)v[3];
    }
    bf16x4 o;
    o[0] = (bf16)acc[0]; o[1] = (bf16)acc[1]; o[2] = (bf16)acc[2]; o[3] = (bf16)acc[3];
    *(bf16x4*)(aggb + (size_t)n * HN + lane * 4) = o;
  }
}

// ---------------- GRU GEMM ----------------
__global__ __launch_bounds__(256) void kgemmF(const bf16* __restrict__ A, const bf16* __restrict__ W,
                                              const float* __restrict__ bias, bf16* __restrict__ C,
                                              int M, int NO) {
  __shared__ bf16 sm[18432];  // As[128][72] | Bs[128][72]
  bf16* As = sm;
  bf16* Bs = sm + 128 * 72;
  const int bm0 = blockIdx.x * 128, bn0 = blockIdx.y * 128;
  const int tid = threadIdx.x, lane = tid & 63, w = tid >> 6;
  const int wm = w >> 1, wn = w & 1, lr = lane & 15, lk = lane >> 4;
  const int lrow = tid >> 3, lcol = (tid & 7) * 8;
  f32x4 acc[4][4] = {};
  for (int k0 = 0; k0 < HN; k0 += 64) {
    #pragma unroll
    for (int p = 0; p < 4; p++) {
      int r = lrow + p * 32;
      int gr = bm0 + r;
      bf16x8 v = (gr < M) ? *(const bf16x8*)(A + (size_t)gr * HN + k0 + lcol) : zero8();
      *(bf16x8*)(&As[r * 72 + lcol]) = v;
      *(bf16x8*)(&Bs[r * 72 + lcol]) = *(const bf16x8*)(W + (size_t)(bn0 + r) * HN + k0 + lcol);
    }
    __syncthreads();
    #pragma unroll
    for (int kk = 0; kk < 2; kk++) {
      bf16x8 af[4], bfr[4];
      #pragma unroll
      for (int m = 0; m < 4; m++) af[m] = *(const bf16x8*)(&As[(wm * 64 + m * 16 + lr) * 72 + kk * 32 + lk * 8]);
      #pragma unroll
      for (int n = 0; n < 4; n++) bfr[n] = *(const bf16x8*)(&Bs[(wn * 64 + n * 16 + lr) * 72 + kk * 32 + lk * 8]);
      #pragma unroll
      for (int m = 0; m < 4; m++)
        #pragma unroll
        for (int n = 0; n < 4; n++)
          acc[m][n] = __builtin_amdgcn_mfma_f32_16x16x32_bf16(af[m], bfr[n], acc[m][n], 0, 0, 0);
    }
    __syncthreads();
  }
  epi_store64<0>(acc, sm + w * 1152, bias, bn0 + wn * 64, C, NO, bm0 + wm * 64, M, lane);
}

// ---------------- head GEMM-1 with fused pair-diff gather ----------------
__global__ __launch_bounds__(256) void kgemmP(const int* __restrict__ pidx, const bf16* __restrict__ Sb,
                                              const bf16* __restrict__ W, const float* __restrict__ bias,
                                              bf16* __restrict__ C, int M, int NO) {
  __shared__ bf16 sm[18432];
  __shared__ int ia[128], ib[128];
  bf16* As = sm;
  bf16* Bs = sm + 128 * 72;
  const int bm0 = blockIdx.x * 128, bn0 = blockIdx.y * 128;
  const int tid = threadIdx.x, lane = tid & 63, w = tid >> 6;
  const int wm = w >> 1, wn = w & 1, lr = lane & 15, lk = lane >> 4;
  const int lrow = tid >> 3, lcol = (tid & 7) * 8;
  if (tid < 128) {
    int p = bm0 + tid;
    int a = 0, b = 0;
    if (p < M) { a = pidx[2 * p]; b = pidx[2 * p + 1]; }
    ia[tid] = a; ib[tid] = b;
  }
  __syncthreads();
  f32x4 acc[4][4] = {};
  for (int k0 = 0; k0 < HN; k0 += 64) {
    #pragma unroll
    for (int p = 0; p < 4; p++) {
      int r = lrow + p * 32;
      bf16x8 va = *(const bf16x8*)(Sb + (size_t)ia[r] * HN + k0 + lcol);
      bf16x8 vb = *(const bf16x8*)(Sb + (size_t)ib[r] * HN + k0 + lcol);
      bf16x8 v;
      #pragma unroll
      for (int j = 0; j < 8; j++) v[j] = (bf16)((float)va[j] - (float)vb[j]);
      *(bf16x8*)(&As[r * 72 + lcol]) = v;
      *(bf16x8*)(&Bs[r * 72 + lcol]) = *(const bf16x8*)(W + (size_t)(bn0 + r) * HN + k0 + lcol);
    }
    __syncthreads();
    #pragma unroll
    for (int kk = 0; kk < 2; kk++) {
      bf16x8 af[4], bfr[4];
      #pragma unroll
      for (int m = 0; m < 4; m++) af[m] = *(const bf16x8*)(&As[(wm * 64 + m * 16 + lr) * 72 + kk * 32 + lk * 8]);
      #pragma unroll
      for (int n = 0; n < 4; n++) bfr[n] = *(const bf16x8*)(&Bs[(wn * 64 + n * 16 + lr) * 72 + kk * 32 + lk * 8]);
      #pragma unroll
      for (int m = 0; m < 4; m++)
        #pragma unroll
        for (int n = 0; n < 4; n++)
          acc[m][n] = __builtin_amdgcn_mfma_f32_16x16x32_bf16(af[m], bfr[n], acc[m][n], 0, 0, 0);
    }
    __syncthreads();
  }
  epi_store64<1>(acc, sm + w * 1152, bias, bn0 + wn * 64, C, NO, bm0 + wm * 64, M, lane);
}

// ---------------- head GEMM-2 ----------------
__global__ __launch_bounds__(256) void kgemmB(const bf16* __restrict__ A, const bf16* __restrict__ W,
                                              const float* __restrict__ bias, bf16* __restrict__ C,
                                              int M, int NO) {
  __shared__ bf16 sm[18432];
  bf16* As = sm;
  bf16* Bs = sm + 128 * 72;
  const int bm0 = blockIdx.x * 128, bn0 = blockIdx.y * 128;
  const int tid = threadIdx.x, lane = tid & 63, w = tid >> 6;
  const int wm = w >> 1, wn = w & 1, lr = lane & 15, lk = lane >> 4;
  const int lrow = tid >> 3, lcol = (tid & 7) * 8;
  f32x4 acc[4][4] = {};
  for (int k0 = 0; k0 < HN; k0 += 64) {
    #pragma unroll
    for (int p = 0; p < 4; p++) {
      int r = lrow + p * 32;
      int gr = bm0 + r;
      bf16x8 v = (gr < M) ? *(const bf16x8*)(A + (size_t)gr * HN + k0 + lcol) : zero8();
      *(bf16x8*)(&As[r * 72 + lcol]) = v;
      *(bf16x8*)(&Bs[r * 72 + lcol]) = *(const bf16x8*)(W + (size_t)(bn0 + r) * HN + k0 + lcol);
    }
    __syncthreads();
    #pragma unroll
    for (int kk = 0; kk < 2; kk++) {
      bf16x8 af[4], bfr[4];
      #pragma unroll
      for (int m = 0; m < 4; m++) af[m] = *(const bf16x8*)(&As[(wm * 64 + m * 16 + lr) * 72 + kk * 32 + lk * 8]);
      #pragma unroll
      for (int n = 0; n < 4; n++) bfr[n] = *(const bf16x8*)(&Bs[(wn * 64 + n * 16 + lr) * 72 + kk * 32 + lk * 8]);
      #pragma unroll
      for (int m = 0; m < 4; m++)
        #pragma unroll
        for (int n = 0; n < 4; n++)
          acc[m][n] = __builtin_amdgcn_mfma_f32_16x16x32_bf16(af[m], bfr[n], acc[m][n], 0, 0, 0);
    }
    __syncthreads();
  }
  epi_store64<1>(acc, sm + w * 1152, bias, bn0 + wn * 64, C, NO, bm0 + wm * 64, M, lane);
}

// ---------------- GRU gate (bf16 state in/out) ----------------
__global__ void kgate(const bf16* __restrict__ gi, const bf16* __restrict__ gh,
                      bf16* __restrict__ Sb, int n, int dorelu) {
  int total = n * 32;
  for (int id = blockIdx.x * blockDim.x + threadIdx.x; id < total; id += gridDim.x * blockDim.x) {
    int i = id >> 5;
    int h = (id & 31) * 8;
    const bf16* pgi = gi + (size_t)i * G3 + h;
    const bf16* pgh = gh + (size_t)i * G3 + h;
    bf16x8 gr8 = *(const bf16x8*)(pgi);
    bf16x8 hr8 = *(const bf16x8*)(pgh);
    bf16x8 gz8 = *(const bf16x8*)(pgi + HN);
    bf16x8 hz8 = *(const bf16x8*)(pgh + HN);
    bf16x8 gn8 = *(const bf16x8*)(pgi + 2 * HN);
    bf16x8 hn8 = *(const bf16x8*)(pgh + 2 * HN);
    bf16* ps = Sb + (size_t)i * HN + h;
    bf16x8 hv8 = *(const bf16x8*)ps;
    bf16x8 ob;
    #pragma unroll
    for (int j = 0; j < 8; j++) {
      float hv = (float)hv8[j];
      float r = sigf((float)gr8[j] + (float)hr8[j]);
      float z = sigf((float)gz8[j] + (float)hz8[j]);
      float nn = tanhf((float)gn8[j] + r * (float)hn8[j]);
      float s = (1.f - z) * nn + z * hv;
      if (dorelu) s = fmaxf(s, 0.f);
      ob[j] = (bf16)s;
    }
    *(bf16x8*)ps = ob;
  }
}

// ---------------- final 20-col head ----------------
__global__ __launch_bounds__(256) void khead_out(const bf16* __restrict__ Hb, const float* __restrict__ W,
                                                 const float* __restrict__ bias, float* __restrict__ out, int P) {
  __shared__ float Wl[KMIXN][256];
  __shared__ float bl[KMIXN];
  for (int i = threadIdx.x; i < KMIXN * 256; i += 256) Wl[i >> 8][i & 255] = W[i];
  if (threadIdx.x < KMIXN) bl[threadIdx.x] = bias[threadIdx.x];
  __syncthreads();
  int lane = threadIdx.x & 63;
  int wv = threadIdx.x >> 6;
  for (int p = blockIdx.x * 4 + wv; p < P; p += gridDim.x * 4) {
    bf16x4 hv = *(const bf16x4*)(Hb + (size_t)p * HN + lane * 4);
    float h0 = (float)hv[0], h1 = (float)hv[1], h2 = (float)hv[2], h3 = (float)hv[3];
    float pk[KMIXN];
    #pragma unroll
    for (int k = 0; k < KMIXN; k++) {
      const float* wr = &Wl[k][lane * 4];
      pk[k] = h0 * wr[0] + h1 * wr[1] + h2 * wr[2] + h3 * wr[3];
    }
    #pragma unroll
    for (int k = 0; k < KMIXN; k++)
      #pragma unroll
      for (int o = 32; o > 0; o >>= 1) pk[k] += __shfl_down(pk[k], o, 64);
    if (lane == 0) {
      #pragma unroll
      for (int k = 0; k < KMIXN; k++) out[(size_t)p * KMIXN + k] = pk[k] + bl[k];
    }
  }
}

static inline size_t alup(size_t x) { return (x + 255) & ~(size_t)255; }

extern "C" void kernel_launch(void* const* d_in, const int* in_sizes, int n_in,
                              void* d_out, int out_size, void* d_ws, size_t ws_size,
                              hipStream_t stream) {
  const int* user_idx = (const int*)d_in[0];
  const int* node_idx_feat = (const int*)d_in[1];
  const float* pos_flag = (const float*)d_in[2];
  const int* edges = (const int*)d_in[3];
  const int* node_idx_gnn = (const int*)d_in[4];
  const int* att_idx = (const int*)d_in[5];
  const float* att_noise = (const float*)d_in[6];
  const float* users = (const float*)d_in[7];
  const float* items = (const float*)d_in[8];
  const float* msg_w1 = (const float*)d_in[9];
  const float* msg_b1 = (const float*)d_in[10];
  const float* msg_w2 = (const float*)d_in[11];
  const float* msg_b2 = (const float*)d_in[12];
  const float* att_w1 = (const float*)d_in[13];
  const float* att_b1 = (const float*)d_in[14];
  const float* att_w2 = (const float*)d_in[15];
  const float* att_b2 = (const float*)d_in[16];
  const float* gru_wih = (const float*)d_in[17];
  const float* gru_bih = (const float*)d_in[18];
  const float* gru_whh = (const float*)d_in[19];
  const float* gru_bhh = (const float*)d_in[20];
  const float* theta_w1 = (const float*)d_in[21];
  const float* theta_b1 = (const float*)d_in[22];
  const float* theta_w2 = (const float*)d_in[23];
  const float* theta_b2 = (const float*)d_in[24];
  const float* theta_w3 = (const float*)d_in[25];
  const float* theta_b3 = (const float*)d_in[26];
  const float* alpha_w1 = (const float*)d_in[27];
  const float* alpha_b1 = (const float*)d_in[28];
  const float* alpha_w2 = (const float*)d_in[29];
  const float* alpha_b2 = (const float*)d_in[30];
  const float* alpha_w3 = (const float*)d_in[31];
  const float* alpha_b3 = (const float*)d_in[32];

  const int N = in_sizes[0];
  const int E = in_sizes[3] / 2;
  const int P = in_sizes[4] / 2;

  float* out_theta = (float*)d_out;
  float* out_alpha = out_theta + (size_t)P * KMIXN;
  float* out_bpr = out_theta + 2 * (size_t)P * KMIXN;

  // ---- workspace carve (~211 MB) ----
  char* ws = (char*)d_ws;
  size_t off = 0;
  bf16* Sb = (bf16*)(ws + off); off += alup((size_t)N * HN * 2);      // 25.6 MB
  const int L2N = 2;
  int wc[11];
  wc[0] = 0;
  wc[1] = wc[0] + L2N * HN * KIN;
  wc[2] = wc[1] + L2N * EFN * KIN;
  wc[3] = wc[2] + L2N * HN * HN;
  wc[4] = wc[3] + L2N * HN * EFN;
  wc[5] = wc[4] + L2N * G3 * HN;
  wc[6] = wc[5] + L2N * G3 * HN;
  wc[7] = wc[6] + HN * HN;
  wc[8] = wc[7] + HN * HN;
  wc[9] = wc[8] + HN * HN;
  wc[10] = wc[9] + HN * HN;
  bf16* wb = (bf16*)(ws + off); off += alup((size_t)wc[10] * 2);      // ~3.1 MB
  bf16* wb_m1 = wb + wc[0];
  bf16* wb_a1 = wb + wc[1];
  bf16* wb_m2 = wb + wc[2];
  bf16* wb_a2 = wb + wc[3];
  bf16* wb_gih = wb + wc[4];
  bf16* wb_ghh = wb + wc[5];
  bf16* wb_tw1 = wb + wc[6];
  bf16* wb_tw2 = wb + wc[7];
  bf16* wb_aw1 = wb + wc[8];
  bf16* wb_aw2 = wb + wc[9];
  int* rp = (int*)(ws + off); off += alup((size_t)(N + 1) * 4);
  int* cur = (int*)(ws + off); off += alup((size_t)N * 4);
  int* csrA = (int*)(ws + off); off += alup((size_t)E * 4);
  int* csrB = (int*)(ws + off); off += alup((size_t)E * 4);
  int* csrE = (int*)(ws + off); off += alup((size_t)E * 4);
  float* scal = (float*)(ws + off); off += 256;
  bf16* aggb = (bf16*)(ws + off); off += alup((size_t)N * HN * 2);    // 25.6 MB
  char* X2 = ws + off;                                                // 153.6 MB transient
  bf16* Hall = (bf16*)X2;                          // E x 384
  size_t szGIb = (size_t)N * G3 * 2;
  bf16* gi = (bf16*)X2;
  bf16* gh = (bf16*)(X2 + szGIb);
  int PC = (P + 1) / 2;
  size_t szH1 = (size_t)PC * HN * 2;
  bf16* h1 = (bf16*)X2;
  bf16* h2 = (bf16*)(X2 + szH1);

  const int gE = (E + 127) / 128;
  const int gN = (N + 127) / 128;

  hipMemsetAsync(rp, 0, (size_t)(N + 1) * 4, stream);
  hipMemsetAsync(scal, 0, 4, stream);
  kdeg<<<512, 256, 0, stream>>>(edges, rp, E);
  kscan<<<1, 1024, 0, stream>>>(rp, N);
  kcpy<<<64, 256, 0, stream>>>(rp, cur, N);
  kfill<<<512, 256, 0, stream>>>(edges, cur, csrA, csrB, csrE, E);
  WList wl;
  wl.s[0] = msg_w1; wl.s[1] = att_w1; wl.s[2] = msg_w2; wl.s[3] = att_w2;
  wl.s[4] = gru_wih; wl.s[5] = gru_whh; wl.s[6] = theta_w1; wl.s[7] = theta_w2;
  wl.s[8] = alpha_w1; wl.s[9] = alpha_w2;
  for (int i = 0; i < 11; i++) wl.c[i] = wc[i];
  kwcvt<<<1024, 256, 0, stream>>>(wl, wb);
  ksum<<<256, 256, 0, stream>>>(pos_flag, N, scal);
  kinit<<<1024, 256, 0, stream>>>(user_idx, node_idx_feat, pos_flag, users, items, Sb, out_bpr, scal, N);

  for (int li = 0; li < 2; li++) {
    kgemmE<<<gE, 512, 0, stream>>>(csrA, csrB, csrE, att_idx, att_noise, Sb,
                                   wb_m1 + (size_t)li * HN * KIN, msg_b1 + li * HN,
                                   wb_a1 + (size_t)li * EFN * KIN, att_b1 + li * EFN,
                                   Hall, E);
    kgemmM2<<<gE, 512, 0, stream>>>(Hall, wb_a2 + (size_t)li * HN * EFN, att_b2 + li * HN,
                                    wb_m2 + (size_t)li * HN * HN, msg_b2 + li * HN, E);
    kagg<<<1024, 256, 0, stream>>>(rp, Hall, aggb, N);
    kgemmF<<<dim3(gN, 6), 256, 0, stream>>>(aggb, wb_gih + (size_t)li * G3 * HN, gru_bih + li * G3, gi, N, G3);
    kgemmF<<<dim3(gN, 6), 256, 0, stream>>>(Sb, wb_ghh + (size_t)li * G3 * HN, gru_bhh + li * G3, gh, N, G3);
    kgate<<<2048, 256, 0, stream>>>(gi, gh, Sb, N, li == 0 ? 1 : 0);
  }

  for (int c = 0; c < 2; c++) {
    int pc0 = c * PC;
    int pcn = (P - pc0 < PC) ? (P - pc0) : PC;
    if (pcn <= 0) break;
    int gPc = (pcn + 127) / 128;
    kgemmP<<<dim3(gPc, 2), 256, 0, stream>>>(node_idx_gnn + (size_t)pc0 * 2, Sb, wb_tw1, theta_b1, h1, pcn, HN);
    kgemmB<<<dim3(gPc, 2), 256, 0, stream>>>(h1, wb_tw2, theta_b2, h2, pcn, HN);
    khead_out<<<4096, 256, 0, stream>>>(h2, theta_w3, theta_b3, out_theta + (size_t)pc0 * KMIXN, pcn);
    kgemmP<<<dim3(gPc, 2), 256, 0, stream>>>(node_idx_gnn + (size_t)pc0 * 2, Sb, wb_aw1, alpha_b1, h1, pcn, HN);
    kgemmB<<<dim3(gPc, 2), 256, 0, stream>>>(h1, wb_aw2, alpha_b2, h2, pcn, HN);
    khead_out<<<4096, 256, 0, stream>>>(h2, alpha_w3, alpha_b3, out_alpha + (size_t)pc0 * KMIXN, pcn);
  }
}